// Round 5
// baseline (712.306 us; speedup 1.0000x reference)
//
#include <hip/hip_runtime.h>
#include <cstdint>

#define NNODES 10000
#define NEDGES 160000
#define TOT_E  (NEDGES + NNODES)
#define HEADS  8

typedef unsigned short u16;
typedef __attribute__((ext_vector_type(8))) short sh8;   // 8 bf16 in 4 VGPRs
typedef __attribute__((ext_vector_type(4))) float f4;    // MFMA accumulator

__device__ inline u16 f2bf(float x) {                    // RNE fp32->bf16
    union { float f; unsigned u; } v; v.f = x;
    unsigned r = v.u + 0x7fffu + ((v.u >> 16) & 1u);
    return (u16)(r >> 16);
}
__device__ inline float bf2f(u16 b) {
    union { unsigned u; float f; } v; v.u = ((unsigned)b) << 16;
    return v.f;
}

__device__ inline void gld16(const u16* g, u16* l) {
    __builtin_amdgcn_global_load_lds(
        (const __attribute__((address_space(1))) void*)g,
        (__attribute__((address_space(3))) void*)l, 16, 0, 0);
}

// ---------------- CSR build (dst-sorted) ----------------
__global__ void count_k(const int* __restrict__ ei, int* __restrict__ deg) {
    int i = blockIdx.x * 256 + threadIdx.x;
    if (i >= TOT_E) return;
    int dst = (i < NEDGES) ? ei[NEDGES + i] : (i - NEDGES);
    atomicAdd(deg + dst, 1);
}

__global__ __launch_bounds__(1024) void scan_k(const int* __restrict__ deg,
                                               int* __restrict__ rows) {
    __shared__ int buf[1024];
    int tid = threadIdx.x;
    int base = tid * 10;
    int loc[10]; int s = 0;
    #pragma unroll
    for (int j = 0; j < 10; j++) {
        int i = base + j;
        loc[j] = s;
        s += (i < NNODES) ? deg[i] : 0;
    }
    buf[tid] = s;
    __syncthreads();
    for (int off = 1; off < 1024; off <<= 1) {
        int t = (tid >= off) ? buf[tid - off] : 0;
        __syncthreads();
        buf[tid] += t;
        __syncthreads();
    }
    int ex = tid ? buf[tid - 1] : 0;
    #pragma unroll
    for (int j = 0; j < 10; j++) {
        int i = base + j;
        if (i < NNODES) rows[i] = ex + loc[j];
    }
    if (tid == 1023) rows[NNODES] = buf[1023];
}

__global__ void scatter_k(const int* __restrict__ ei, const int* __restrict__ rows,
                          int* __restrict__ cursor, int* __restrict__ esrc) {
    int i = blockIdx.x * 256 + threadIdx.x;
    if (i >= TOT_E) return;
    int src, dst;
    if (i < NEDGES) { src = ei[i]; dst = ei[NEDGES + i]; }
    else            { src = i - NEDGES; dst = src; }
    int pos = atomicAdd(cursor + dst, 1);
    esrc[rows[dst] + pos] = src;
}

// ---------------- fp32 -> (hi,lo) bf16 split ----------------
__global__ void split4_k(const float* __restrict__ in, u16* __restrict__ hi,
                         u16* __restrict__ lo, int n4) {
    int i = blockIdx.x * 256 + threadIdx.x;
    if (i >= n4) return;
    float4 v = ((const float4*)in)[i];
    ushort4 h, l;
    h.x = f2bf(v.x); l.x = f2bf(v.x - bf2f(h.x));
    h.y = f2bf(v.y); l.y = f2bf(v.y - bf2f(h.y));
    h.z = f2bf(v.z); l.z = f2bf(v.z - bf2f(h.z));
    h.w = f2bf(v.w); l.w = f2bf(v.w - bf2f(h.w));
    ((ushort4*)hi)[i] = h;
    ((ushort4*)lo)[i] = l;
}

// ---------------- split-bf16 MFMA GEMM + fused alpha partials ----------------
// C[M,N] = A[M,K] * W[N,K]^T; epilogue also accumulates
// asrc[n,h] += sum_c h[n,h,c]*a_s[h,c] (and adst) via atomics (asrc/adst zeroed).
__global__ __launch_bounds__(256) void gemm_mfma(
    const u16* __restrict__ Ah, const u16* __restrict__ Al,
    const u16* __restrict__ Bh, const u16* __restrict__ Bl,
    float* __restrict__ C, int M, int N, int K,
    const float* __restrict__ a_s, const float* __restrict__ a_d,
    float* __restrict__ asrc, float* __restrict__ adst, int Chead)
{
    __shared__ u16 sAh[4096], sAl[4096], sBh[4096], sBl[4096];
    const int t = threadIdx.x, lane = t & 63, w = t >> 6;
    const int row0 = blockIdx.y * 128, col0 = blockIdx.x * 128;
    const int wm = w & 1, wn = w >> 1;
    const int l15 = lane & 15, quad = lane >> 4;

    const int rs0 = (w * 2) * 16 + (lane >> 2);
    const int rs1 = (w * 2 + 1) * 16 + (lane >> 2);
    const int oct = lane & 3;
    int ga0 = row0 + rs0; if (ga0 >= M) ga0 = M - 1;
    int ga1 = row0 + rs1; if (ga1 >= M) ga1 = M - 1;
    const int gb0 = col0 + rs0, gb1 = col0 + rs1;
    const u16* pA0h = Ah + (size_t)ga0 * K + oct * 8;
    const u16* pA1h = Ah + (size_t)ga1 * K + oct * 8;
    const u16* pA0l = Al + (size_t)ga0 * K + oct * 8;
    const u16* pA1l = Al + (size_t)ga1 * K + oct * 8;
    const u16* pB0h = Bh + (size_t)gb0 * K + oct * 8;
    const u16* pB1h = Bh + (size_t)gb1 * K + oct * 8;
    const u16* pB0l = Bl + (size_t)gb0 * K + oct * 8;
    const u16* pB1l = Bl + (size_t)gb1 * K + oct * 8;
    const int cb0 = (w * 2) * 512, cb1 = (w * 2 + 1) * 512;

    const int aoff = (wm * 64 + l15) * 32 + quad * 8;
    const int boff = (wn * 64 + l15) * 32 + quad * 8;

    f4 acc[4][4];
    #pragma unroll
    for (int i = 0; i < 4; i++)
        #pragma unroll
        for (int j = 0; j < 4; j++)
            acc[i][j] = (f4){0.f, 0.f, 0.f, 0.f};

    for (int k0 = 0; k0 < K; k0 += 32) {
        gld16(pA0h, &sAh[cb0]); gld16(pA1h, &sAh[cb1]);
        gld16(pA0l, &sAl[cb0]); gld16(pA1l, &sAl[cb1]);
        gld16(pB0h, &sBh[cb0]); gld16(pB1h, &sBh[cb1]);
        gld16(pB0l, &sBl[cb0]); gld16(pB1l, &sBl[cb1]);
        pA0h += 32; pA1h += 32; pA0l += 32; pA1l += 32;
        pB0h += 32; pB1h += 32; pB0l += 32; pB1l += 32;
        __syncthreads();

        sh8 ah[4], al[4];
        #pragma unroll
        for (int i = 0; i < 4; i++) {
            ah[i] = *(const sh8*)&sAh[aoff + i * 512];
            al[i] = *(const sh8*)&sAl[aoff + i * 512];
        }
        #pragma unroll
        for (int j = 0; j < 4; j++) {
            sh8 bh = *(const sh8*)&sBh[boff + j * 512];
            sh8 bl = *(const sh8*)&sBl[boff + j * 512];
            #pragma unroll
            for (int i = 0; i < 4; i++) {
                acc[i][j] = __builtin_amdgcn_mfma_f32_16x16x32_bf16(ah[i], bh, acc[i][j], 0, 0, 0);
                acc[i][j] = __builtin_amdgcn_mfma_f32_16x16x32_bf16(ah[i], bl, acc[i][j], 0, 0, 0);
                acc[i][j] = __builtin_amdgcn_mfma_f32_16x16x32_bf16(al[i], bh, acc[i][j], 0, 0, 0);
            }
        }
        __syncthreads();
    }

    // alpha coefficients for this wave's 64-channel span (span always within one head)
    const int span0 = col0 + wn * 64;
    const int hd = span0 / Chead;
    float av[4], dv[4];
    #pragma unroll
    for (int j = 0; j < 4; j++) {
        av[j] = a_s[span0 + j * 16 + l15];
        dv[j] = a_d[span0 + j * 16 + l15];
    }

    // epilogue: C/D layout col=lane&15, row=quad*4+reg; store C + alpha partials
    #pragma unroll
    for (int i = 0; i < 4; i++) {
        #pragma unroll
        for (int r = 0; r < 4; r++) {
            int gr = row0 + wm * 64 + i * 16 + quad * 4 + r;
            float s1 = 0.f, s2 = 0.f;
            #pragma unroll
            for (int j = 0; j < 4; j++) {
                float v = acc[i][j][r];
                s1 += v * av[j];
                s2 += v * dv[j];
            }
            #pragma unroll
            for (int m = 1; m < 16; m <<= 1) {
                s1 += __shfl_xor(s1, m);
                s2 += __shfl_xor(s2, m);
            }
            if (gr < M) {
                float* cp = C + (size_t)gr * N + span0 + l15;
                #pragma unroll
                for (int j = 0; j < 4; j++)
                    cp[j * 16] = acc[i][j][r];
                if (l15 == 0) {
                    atomicAdd(asrc + gr * HEADS + hd, s1);
                    atomicAdd(adst + gr * HEADS + hd, s2);
                }
            }
        }
    }
}

// ---------------- softmax + aggregation ----------------
// One block per node, 8 waves = 8 heads. No max-subtraction (logits bounded;
// p/s scale-invariant). LPE = C/4 lanes per edge (always float4 loads),
// EPW = 64/LPE edges per pass, U batched passes in flight.
// MODE 0: concat +bias +ELU + bf16 hi/lo split. MODE 1: LDS head-mean + bias.
template<int C, int MODE>
__global__ __launch_bounds__(512) void agg_k(const float* __restrict__ h,
                                             const float* __restrict__ asrc,
                                             const float* __restrict__ adst,
                                             const int* __restrict__ rows,
                                             const int* __restrict__ esrc,
                                             const float* __restrict__ bias,
                                             u16* __restrict__ oh,
                                             u16* __restrict__ ol,
                                             float* __restrict__ outf) {
    constexpr int LPE = C / 4;
    constexpr int EPW = 64 / LPE;
    constexpr int U   = (LPE == 64) ? 16 : 8;
    __shared__ float red[MODE == 1 ? HEADS * 256 : 8];

    const int n    = blockIdx.x;
    const int hd   = threadIdx.x >> 6;
    const int lane = threadIdx.x & 63;
    const int sub  = lane / LPE;
    const int cl   = lane % LPE;
    const int beg = rows[n], end = rows[n + 1], deg = end - beg;
    const float ad = adst[n * HEADS + hd];

    float4 acc = {0.f, 0.f, 0.f, 0.f};

    auto gather = [&](int e, float pw, int cdeg) {
        for (int j = 0; j < cdeg; j += EPW * U) {
            int   sn[U]; float wg[U];
            #pragma unroll
            for (int u = 0; u < U; u++) {
                int idx = j + sub + EPW * u;
                int   ss = __shfl(e, idx);
                float ww = __shfl(pw, idx);
                bool ok = idx < cdeg;
                sn[u] = ok ? ss : 0;
                wg[u] = ok ? ww : 0.f;
            }
            float4 v[U];
            #pragma unroll
            for (int u = 0; u < U; u++)
                v[u] = *(const float4*)(h + (size_t)sn[u] * (HEADS * C) + hd * C + cl * 4);
            #pragma unroll
            for (int u = 0; u < U; u++) {
                acc.x += wg[u] * v[u].x; acc.y += wg[u] * v[u].y;
                acc.z += wg[u] * v[u].z; acc.w += wg[u] * v[u].w;
            }
        }
    };

    if (deg <= 64) {
        int e = 0; float p = 0.f;
        if (lane < deg) {
            e = esrc[beg + lane];
            float lg = asrc[e * HEADS + hd] + ad;
            lg = (lg > 0.f) ? lg : 0.2f * lg;
            p = __expf(lg);
        }
        float s = p;
        #pragma unroll
        for (int off = 32; off; off >>= 1) s += __shfl_xor(s, off);
        float pw = p / (s + 1e-16f);
        gather(e, pw, deg);
    } else {
        float ssum = 0.f;
        for (int i = beg + lane; i < end; i += 64) {
            float lg = asrc[esrc[i] * HEADS + hd] + ad;
            lg = (lg > 0.f) ? lg : 0.2f * lg;
            ssum += __expf(lg);
        }
        #pragma unroll
        for (int off = 32; off; off >>= 1) ssum += __shfl_xor(ssum, off);
        float inv = 1.f / (ssum + 1e-16f);
        for (int c0 = beg; c0 < end; c0 += 64) {
            int cdeg = min(64, end - c0);
            int e = 0; float pw = 0.f;
            if (lane < cdeg) {
                e = esrc[c0 + lane];
                float lg = asrc[e * HEADS + hd] + ad;
                lg = (lg > 0.f) ? lg : 0.2f * lg;
                pw = __expf(lg) * inv;
            }
            gather(e, pw, cdeg);
        }
    }

    #pragma unroll
    for (int m = LPE; m < 64; m <<= 1) {
        acc.x += __shfl_xor(acc.x, m); acc.y += __shfl_xor(acc.y, m);
        acc.z += __shfl_xor(acc.z, m); acc.w += __shfl_xor(acc.w, m);
    }

    if constexpr (MODE == 0) {
        if (sub == 0) {
            const float* bp = bias + hd * C + cl * 4;
            float4 b = *(const float4*)bp;
            float r[4] = {acc.x + b.x, acc.y + b.y, acc.z + b.z, acc.w + b.w};
            ushort4 hv, lv;
            #pragma unroll
            for (int j = 0; j < 4; j++)
                r[j] = (r[j] > 0.f) ? r[j] : (expf(r[j]) - 1.f);   // ELU
            hv.x = f2bf(r[0]); lv.x = f2bf(r[0] - bf2f(hv.x));
            hv.y = f2bf(r[1]); lv.y = f2bf(r[1] - bf2f(hv.y));
            hv.z = f2bf(r[2]); lv.z = f2bf(r[2] - bf2f(hv.z));
            hv.w = f2bf(r[3]); lv.w = f2bf(r[3] - bf2f(hv.w));
            size_t base = (size_t)n * (HEADS * C) + hd * C + cl * 4;
            *(ushort4*)(oh + base) = hv;
            *(ushort4*)(ol + base) = lv;
        }
    } else {
        *(float4*)&red[hd * 256 + lane * 4] = acc;
        __syncthreads();
        int tid = threadIdx.x;
        if (tid < 256) {
            float s = 0.f;
            #pragma unroll
            for (int hh = 0; hh < HEADS; hh++) s += red[hh * 256 + tid];
            outf[(size_t)n * 256 + tid] = s * 0.125f + bias[tid];
        }
    }
}

// ---------------- launch ----------------
extern "C" void kernel_launch(void* const* d_in, const int* in_sizes, int n_in,
                              void* d_out, int out_size, void* d_ws, size_t ws_size,
                              hipStream_t stream) {
    const float* x   = (const float*)d_in[0];
    const int*   ei  = (const int*)d_in[1];
    const float* W1  = (const float*)d_in[2];
    const float* as1 = (const float*)d_in[3];
    const float* ad1 = (const float*)d_in[4];
    const float* b1  = (const float*)d_in[5];
    const float* W2  = (const float*)d_in[6];
    const float* as2 = (const float*)d_in[7];
    const float* ad2 = (const float*)d_in[8];
    const float* b2  = (const float*)d_in[9];
    const float* W3  = (const float*)d_in[10];
    const float* as3 = (const float*)d_in[11];
    const float* ad3 = (const float*)d_in[12];
    const float* b3  = (const float*)d_in[13];
    float* out = (float*)d_out;

    int* deg    = (int*)d_ws;
    int* cursor = deg + 10240;
    int* rows   = cursor + 10240;
    int* esrc   = rows + 10240;
    float* asrc = (float*)(esrc + 170240);   // 81920 floats
    float* adst = asrc + 81920;              // 81920 floats (contiguous with asrc)
    float* H    = adst + 81920;
    u16* Ahg    = (u16*)(H + (size_t)NNODES * 2048);
    u16* Alg    = Ahg + (size_t)NNODES * 1024;
    u16* Whg    = Alg + (size_t)NNODES * 1024;
    u16* Wlg    = Whg + (size_t)2048 * 1024;

    hipMemsetAsync(deg, 0, 2 * 10240 * sizeof(int), stream);

    count_k<<<(TOT_E + 255) / 256, 256, 0, stream>>>(ei, deg);
    scan_k<<<1, 1024, 0, stream>>>(deg, rows);
    scatter_k<<<(TOT_E + 255) / 256, 256, 0, stream>>>(ei, rows, cursor, esrc);

    const int rowBlocks = (NNODES + 127) / 128;

    // ---- layer 1: IN=256 -> 8x64 concat ----
    split4_k<<<(NNODES * 256 / 4 + 255) / 256, 256, 0, stream>>>(x, Ahg, Alg, NNODES * 256 / 4);
    split4_k<<<(512 * 256 / 4 + 255) / 256, 256, 0, stream>>>(W1, Whg, Wlg, 512 * 256 / 4);
    hipMemsetAsync(asrc, 0, 2 * 81920 * sizeof(float), stream);
    gemm_mfma<<<dim3(4, rowBlocks), 256, 0, stream>>>(Ahg, Alg, Whg, Wlg, H, NNODES, 512, 256,
                                                      as1, ad1, asrc, adst, 64);
    agg_k<64, 0><<<NNODES, 512, 0, stream>>>(H, asrc, adst, rows, esrc, b1, Ahg, Alg, nullptr);

    // ---- layer 2: 512 -> 8x128 concat ----
    split4_k<<<(1024 * 512 / 4 + 255) / 256, 256, 0, stream>>>(W2, Whg, Wlg, 1024 * 512 / 4);
    hipMemsetAsync(asrc, 0, 2 * 81920 * sizeof(float), stream);
    gemm_mfma<<<dim3(8, rowBlocks), 256, 0, stream>>>(Ahg, Alg, Whg, Wlg, H, NNODES, 1024, 512,
                                                      as2, ad2, asrc, adst, 128);
    agg_k<128, 0><<<NNODES, 512, 0, stream>>>(H, asrc, adst, rows, esrc, b2, Ahg, Alg, nullptr);

    // ---- layer 3: 1024 -> 8x256 mean ----
    split4_k<<<(2048 * 1024 / 4 + 255) / 256, 256, 0, stream>>>(W3, Whg, Wlg, 2048 * 1024 / 4);
    hipMemsetAsync(asrc, 0, 2 * 81920 * sizeof(float), stream);
    gemm_mfma<<<dim3(16, rowBlocks), 256, 0, stream>>>(Ahg, Alg, Whg, Wlg, H, NNODES, 2048, 1024,
                                                      as3, ad3, asrc, adst, 256);
    agg_k<256, 1><<<NNODES, 512, 0, stream>>>(H, asrc, adst, rows, esrc, b3, nullptr, nullptr, out);
}

// Round 6
// 628.393 us; speedup vs baseline: 1.1335x; 1.1335x over previous
//
#include <hip/hip_runtime.h>
#include <cstdint>

#define NNODES 10000
#define NEDGES 160000
#define TOT_E  (NEDGES + NNODES)
#define HEADS  8

typedef unsigned short u16;
typedef __attribute__((ext_vector_type(8))) short sh8;     // 8 bf16 in 4 VGPRs
typedef __attribute__((ext_vector_type(4))) float f4;      // MFMA accumulator
typedef __attribute__((ext_vector_type(4))) _Float16 h4;   // 4 fp16 (8B)

__device__ inline u16 f2bf(float x) {                    // RNE fp32->bf16
    union { float f; unsigned u; } v; v.f = x;
    unsigned r = v.u + 0x7fffu + ((v.u >> 16) & 1u);
    return (u16)(r >> 16);
}
__device__ inline float bf2f(u16 b) {
    union { unsigned u; float f; } v; v.u = ((unsigned)b) << 16;
    return v.f;
}
__device__ inline u16 f2h(float x) {
    union { _Float16 h; u16 u; } c; c.h = (_Float16)x; return c.u;
}

__device__ inline void gld16(const u16* g, u16* l) {
    __builtin_amdgcn_global_load_lds(
        (const __attribute__((address_space(1))) void*)g,
        (__attribute__((address_space(3))) void*)l, 16, 0, 0);
}

// ---------------- CSR build (dst-sorted) ----------------
__global__ void count_k(const int* __restrict__ ei, int* __restrict__ deg) {
    int i = blockIdx.x * 256 + threadIdx.x;
    if (i >= TOT_E) return;
    int dst = (i < NEDGES) ? ei[NEDGES + i] : (i - NEDGES);
    atomicAdd(deg + dst, 1);
}

__global__ __launch_bounds__(1024) void scan_k(const int* __restrict__ deg,
                                               int* __restrict__ rows) {
    __shared__ int buf[1024];
    int tid = threadIdx.x;
    int base = tid * 10;
    int loc[10]; int s = 0;
    #pragma unroll
    for (int j = 0; j < 10; j++) {
        int i = base + j;
        loc[j] = s;
        s += (i < NNODES) ? deg[i] : 0;
    }
    buf[tid] = s;
    __syncthreads();
    for (int off = 1; off < 1024; off <<= 1) {
        int t = (tid >= off) ? buf[tid - off] : 0;
        __syncthreads();
        buf[tid] += t;
        __syncthreads();
    }
    int ex = tid ? buf[tid - 1] : 0;
    #pragma unroll
    for (int j = 0; j < 10; j++) {
        int i = base + j;
        if (i < NNODES) rows[i] = ex + loc[j];
    }
    if (tid == 1023) rows[NNODES] = buf[1023];
}

__global__ void scatter_k(const int* __restrict__ ei, const int* __restrict__ rows,
                          int* __restrict__ cursor, int* __restrict__ esrc) {
    int i = blockIdx.x * 256 + threadIdx.x;
    if (i >= TOT_E) return;
    int src, dst;
    if (i < NEDGES) { src = ei[i]; dst = ei[NEDGES + i]; }
    else            { src = i - NEDGES; dst = src; }
    int pos = atomicAdd(cursor + dst, 1);
    esrc[rows[dst] + pos] = src;
}

// ---------------- fp32 -> (hi,lo) bf16 split ----------------
__global__ void split4_k(const float* __restrict__ in, u16* __restrict__ hi,
                         u16* __restrict__ lo, int n4) {
    int i = blockIdx.x * 256 + threadIdx.x;
    if (i >= n4) return;
    float4 v = ((const float4*)in)[i];
    ushort4 h, l;
    h.x = f2bf(v.x); l.x = f2bf(v.x - bf2f(h.x));
    h.y = f2bf(v.y); l.y = f2bf(v.y - bf2f(h.y));
    h.z = f2bf(v.z); l.z = f2bf(v.z - bf2f(h.z));
    h.w = f2bf(v.w); l.w = f2bf(v.w - bf2f(h.w));
    ((ushort4*)hi)[i] = h;
    ((ushort4*)lo)[i] = l;
}

// ---------------- split-bf16 MFMA GEMM + fused alpha partials ----------------
// C = A * W^T; epilogue accumulates asrc/adst partials (atomics, pre-zeroed).
// F16OUT: store result to C16 as fp16 (layer 3; agg-only consumer), else fp32 C.
template<int F16OUT>
__global__ __launch_bounds__(256) void gemm_mfma(
    const u16* __restrict__ Ah, const u16* __restrict__ Al,
    const u16* __restrict__ Bh, const u16* __restrict__ Bl,
    float* __restrict__ C, u16* __restrict__ C16, int M, int N, int K,
    const float* __restrict__ a_s, const float* __restrict__ a_d,
    float* __restrict__ asrc, float* __restrict__ adst, int Chead)
{
    __shared__ u16 sAh[4096], sAl[4096], sBh[4096], sBl[4096];
    const int t = threadIdx.x, lane = t & 63, w = t >> 6;
    const int row0 = blockIdx.y * 128, col0 = blockIdx.x * 128;
    const int wm = w & 1, wn = w >> 1;
    const int l15 = lane & 15, quad = lane >> 4;

    const int rs0 = (w * 2) * 16 + (lane >> 2);
    const int rs1 = (w * 2 + 1) * 16 + (lane >> 2);
    const int oct = lane & 3;
    int ga0 = row0 + rs0; if (ga0 >= M) ga0 = M - 1;
    int ga1 = row0 + rs1; if (ga1 >= M) ga1 = M - 1;
    const int gb0 = col0 + rs0, gb1 = col0 + rs1;
    const u16* pA0h = Ah + (size_t)ga0 * K + oct * 8;
    const u16* pA1h = Ah + (size_t)ga1 * K + oct * 8;
    const u16* pA0l = Al + (size_t)ga0 * K + oct * 8;
    const u16* pA1l = Al + (size_t)ga1 * K + oct * 8;
    const u16* pB0h = Bh + (size_t)gb0 * K + oct * 8;
    const u16* pB1h = Bh + (size_t)gb1 * K + oct * 8;
    const u16* pB0l = Bl + (size_t)gb0 * K + oct * 8;
    const u16* pB1l = Bl + (size_t)gb1 * K + oct * 8;
    const int cb0 = (w * 2) * 512, cb1 = (w * 2 + 1) * 512;

    const int aoff = (wm * 64 + l15) * 32 + quad * 8;
    const int boff = (wn * 64 + l15) * 32 + quad * 8;

    f4 acc[4][4];
    #pragma unroll
    for (int i = 0; i < 4; i++)
        #pragma unroll
        for (int j = 0; j < 4; j++)
            acc[i][j] = (f4){0.f, 0.f, 0.f, 0.f};

    for (int k0 = 0; k0 < K; k0 += 32) {
        gld16(pA0h, &sAh[cb0]); gld16(pA1h, &sAh[cb1]);
        gld16(pA0l, &sAl[cb0]); gld16(pA1l, &sAl[cb1]);
        gld16(pB0h, &sBh[cb0]); gld16(pB1h, &sBh[cb1]);
        gld16(pB0l, &sBl[cb0]); gld16(pB1l, &sBl[cb1]);
        pA0h += 32; pA1h += 32; pA0l += 32; pA1l += 32;
        pB0h += 32; pB1h += 32; pB0l += 32; pB1l += 32;
        __syncthreads();

        sh8 ah[4], al[4];
        #pragma unroll
        for (int i = 0; i < 4; i++) {
            ah[i] = *(const sh8*)&sAh[aoff + i * 512];
            al[i] = *(const sh8*)&sAl[aoff + i * 512];
        }
        #pragma unroll
        for (int j = 0; j < 4; j++) {
            sh8 bh = *(const sh8*)&sBh[boff + j * 512];
            sh8 bl = *(const sh8*)&sBl[boff + j * 512];
            #pragma unroll
            for (int i = 0; i < 4; i++) {
                acc[i][j] = __builtin_amdgcn_mfma_f32_16x16x32_bf16(ah[i], bh, acc[i][j], 0, 0, 0);
                acc[i][j] = __builtin_amdgcn_mfma_f32_16x16x32_bf16(ah[i], bl, acc[i][j], 0, 0, 0);
                acc[i][j] = __builtin_amdgcn_mfma_f32_16x16x32_bf16(al[i], bh, acc[i][j], 0, 0, 0);
            }
        }
        __syncthreads();
    }

    const int span0 = col0 + wn * 64;
    const int hd = span0 / Chead;
    float av[4], dv[4];
    #pragma unroll
    for (int j = 0; j < 4; j++) {
        av[j] = a_s[span0 + j * 16 + l15];
        dv[j] = a_d[span0 + j * 16 + l15];
    }

    // epilogue: C/D layout col=lane&15, row=quad*4+reg
    #pragma unroll
    for (int i = 0; i < 4; i++) {
        #pragma unroll
        for (int r = 0; r < 4; r++) {
            int gr = row0 + wm * 64 + i * 16 + quad * 4 + r;
            float s1 = 0.f, s2 = 0.f;
            #pragma unroll
            for (int j = 0; j < 4; j++) {
                float v = acc[i][j][r];
                s1 += v * av[j];
                s2 += v * dv[j];
            }
            #pragma unroll
            for (int m = 1; m < 16; m <<= 1) {
                s1 += __shfl_xor(s1, m);
                s2 += __shfl_xor(s2, m);
            }
            if (gr < M) {
                if constexpr (F16OUT) {
                    u16* cp = C16 + (size_t)gr * N + span0 + l15;
                    #pragma unroll
                    for (int j = 0; j < 4; j++)
                        cp[j * 16] = f2h(acc[i][j][r]);
                } else {
                    float* cp = C + (size_t)gr * N + span0 + l15;
                    #pragma unroll
                    for (int j = 0; j < 4; j++)
                        cp[j * 16] = acc[i][j][r];
                }
                if (l15 == 0) {
                    atomicAdd(asrc + gr * HEADS + hd, s1);
                    atomicAdd(adst + gr * HEADS + hd, s2);
                }
            }
        }
    }
}

// ---------------- softmax + aggregation ----------------
// One block per node, 8 waves = 8 heads. No max-subtraction (logits bounded;
// p/s scale-invariant). LPE = C/4 lanes per edge; U batched edge-passes in
// flight. MODE 0: fp32 h gather, concat +bias +ELU + bf16 hi/lo split.
// MODE 1: fp16 h gather (layer 3), LDS head-mean + bias, coalesced store.
template<int C, int MODE>
__global__ __launch_bounds__(512) void agg_k(const float* __restrict__ h,
                                             const u16* __restrict__ h16,
                                             const float* __restrict__ asrc,
                                             const float* __restrict__ adst,
                                             const int* __restrict__ rows,
                                             const int* __restrict__ esrc,
                                             const float* __restrict__ bias,
                                             u16* __restrict__ oh,
                                             u16* __restrict__ ol,
                                             float* __restrict__ outf) {
    constexpr int LPE = C / 4;
    constexpr int EPW = 64 / LPE;
    constexpr int U   = (LPE == 64) ? 16 : (LPE == 32) ? 12 : 8;
    __shared__ float red[MODE == 1 ? HEADS * 256 : 8];

    const int n    = blockIdx.x;
    const int hd   = threadIdx.x >> 6;
    const int lane = threadIdx.x & 63;
    const int sub  = lane / LPE;
    const int cl   = lane % LPE;
    const int beg = rows[n], end = rows[n + 1], deg = end - beg;
    const float ad = adst[n * HEADS + hd];

    float4 acc = {0.f, 0.f, 0.f, 0.f};

    auto gather = [&](int e, float pw, int cdeg) {
        for (int j = 0; j < cdeg; j += EPW * U) {
            int   sn[U]; float wg[U];
            #pragma unroll
            for (int u = 0; u < U; u++) {
                int idx = j + sub + EPW * u;
                int   ss = __shfl(e, idx);
                float ww = __shfl(pw, idx);
                bool ok = idx < cdeg;
                sn[u] = ok ? ss : 0;
                wg[u] = ok ? ww : 0.f;
            }
            if constexpr (MODE == 1) {
                h4 v[U];
                #pragma unroll
                for (int u = 0; u < U; u++)
                    v[u] = *(const h4*)(h16 + (size_t)sn[u] * (HEADS * C) + hd * C + cl * 4);
                #pragma unroll
                for (int u = 0; u < U; u++) {
                    acc.x += wg[u] * (float)v[u].x; acc.y += wg[u] * (float)v[u].y;
                    acc.z += wg[u] * (float)v[u].z; acc.w += wg[u] * (float)v[u].w;
                }
            } else {
                float4 v[U];
                #pragma unroll
                for (int u = 0; u < U; u++)
                    v[u] = *(const float4*)(h + (size_t)sn[u] * (HEADS * C) + hd * C + cl * 4);
                #pragma unroll
                for (int u = 0; u < U; u++) {
                    acc.x += wg[u] * v[u].x; acc.y += wg[u] * v[u].y;
                    acc.z += wg[u] * v[u].z; acc.w += wg[u] * v[u].w;
                }
            }
        }
    };

    if (deg <= 64) {
        int e = 0; float p = 0.f;
        if (lane < deg) {
            e = esrc[beg + lane];
            float lg = asrc[e * HEADS + hd] + ad;
            lg = (lg > 0.f) ? lg : 0.2f * lg;
            p = __expf(lg);
        }
        float s = p;
        #pragma unroll
        for (int off = 32; off; off >>= 1) s += __shfl_xor(s, off);
        float pw = p / (s + 1e-16f);
        gather(e, pw, deg);
    } else {
        float ssum = 0.f;
        for (int i = beg + lane; i < end; i += 64) {
            float lg = asrc[esrc[i] * HEADS + hd] + ad;
            lg = (lg > 0.f) ? lg : 0.2f * lg;
            ssum += __expf(lg);
        }
        #pragma unroll
        for (int off = 32; off; off >>= 1) ssum += __shfl_xor(ssum, off);
        float inv = 1.f / (ssum + 1e-16f);
        for (int c0 = beg; c0 < end; c0 += 64) {
            int cdeg = min(64, end - c0);
            int e = 0; float pw = 0.f;
            if (lane < cdeg) {
                e = esrc[c0 + lane];
                float lg = asrc[e * HEADS + hd] + ad;
                lg = (lg > 0.f) ? lg : 0.2f * lg;
                pw = __expf(lg) * inv;
            }
            gather(e, pw, cdeg);
        }
    }

    #pragma unroll
    for (int m = LPE; m < 64; m <<= 1) {
        acc.x += __shfl_xor(acc.x, m); acc.y += __shfl_xor(acc.y, m);
        acc.z += __shfl_xor(acc.z, m); acc.w += __shfl_xor(acc.w, m);
    }

    if constexpr (MODE == 0) {
        if (sub == 0) {
            const float* bp = bias + hd * C + cl * 4;
            float4 b = *(const float4*)bp;
            float r[4] = {acc.x + b.x, acc.y + b.y, acc.z + b.z, acc.w + b.w};
            ushort4 hv, lv;
            #pragma unroll
            for (int j = 0; j < 4; j++)
                r[j] = (r[j] > 0.f) ? r[j] : (expf(r[j]) - 1.f);   // ELU
            hv.x = f2bf(r[0]); lv.x = f2bf(r[0] - bf2f(hv.x));
            hv.y = f2bf(r[1]); lv.y = f2bf(r[1] - bf2f(hv.y));
            hv.z = f2bf(r[2]); lv.z = f2bf(r[2] - bf2f(hv.z));
            hv.w = f2bf(r[3]); lv.w = f2bf(r[3] - bf2f(hv.w));
            size_t base = (size_t)n * (HEADS * C) + hd * C + cl * 4;
            *(ushort4*)(oh + base) = hv;
            *(ushort4*)(ol + base) = lv;
        }
    } else {
        *(float4*)&red[hd * 256 + lane * 4] = acc;
        __syncthreads();
        int tid = threadIdx.x;
        if (tid < 256) {
            float s = 0.f;
            #pragma unroll
            for (int hh = 0; hh < HEADS; hh++) s += red[hh * 256 + tid];
            outf[(size_t)n * 256 + tid] = s * 0.125f + bias[tid];
        }
    }
}

// ---------------- launch ----------------
extern "C" void kernel_launch(void* const* d_in, const int* in_sizes, int n_in,
                              void* d_out, int out_size, void* d_ws, size_t ws_size,
                              hipStream_t stream) {
    const float* x   = (const float*)d_in[0];
    const int*   ei  = (const int*)d_in[1];
    const float* W1  = (const float*)d_in[2];
    const float* as1 = (const float*)d_in[3];
    const float* ad1 = (const float*)d_in[4];
    const float* b1  = (const float*)d_in[5];
    const float* W2  = (const float*)d_in[6];
    const float* as2 = (const float*)d_in[7];
    const float* ad2 = (const float*)d_in[8];
    const float* b2  = (const float*)d_in[9];
    const float* W3  = (const float*)d_in[10];
    const float* as3 = (const float*)d_in[11];
    const float* ad3 = (const float*)d_in[12];
    const float* b3  = (const float*)d_in[13];
    float* out = (float*)d_out;

    int* deg    = (int*)d_ws;
    int* cursor = deg + 10240;
    int* rows   = cursor + 10240;
    int* esrc   = rows + 10240;
    float* asrc = (float*)(esrc + 170240);   // 81920 floats
    float* adst = asrc + 81920;              // 81920 floats (contiguous)
    float* H    = adst + 81920;              // region: NNODES*2048 floats (80MB)
    u16* Hh     = (u16*)(H + (size_t)NNODES * 1024);   // fp16 H-L3 overlays upper half
    u16* Ahg    = (u16*)(H + (size_t)NNODES * 2048);
    u16* Alg    = Ahg + (size_t)NNODES * 1024;
    u16* Whg    = Alg + (size_t)NNODES * 1024;
    u16* Wlg    = Whg + (size_t)2048 * 1024;

    hipMemsetAsync(deg, 0, 2 * 10240 * sizeof(int), stream);

    count_k<<<(TOT_E + 255) / 256, 256, 0, stream>>>(ei, deg);
    scan_k<<<1, 1024, 0, stream>>>(deg, rows);
    scatter_k<<<(TOT_E + 255) / 256, 256, 0, stream>>>(ei, rows, cursor, esrc);

    const int rowBlocks = (NNODES + 127) / 128;

    // ---- layer 1: IN=256 -> 8x64 concat ----
    split4_k<<<(NNODES * 256 / 4 + 255) / 256, 256, 0, stream>>>(x, Ahg, Alg, NNODES * 256 / 4);
    split4_k<<<(512 * 256 / 4 + 255) / 256, 256, 0, stream>>>(W1, Whg, Wlg, 512 * 256 / 4);
    hipMemsetAsync(asrc, 0, 2 * 81920 * sizeof(float), stream);
    gemm_mfma<0><<<dim3(4, rowBlocks), 256, 0, stream>>>(Ahg, Alg, Whg, Wlg, H, nullptr,
                                                         NNODES, 512, 256, as1, ad1, asrc, adst, 64);
    agg_k<64, 0><<<NNODES, 512, 0, stream>>>(H, nullptr, asrc, adst, rows, esrc, b1, Ahg, Alg, nullptr);

    // ---- layer 2: 512 -> 8x128 concat ----
    split4_k<<<(1024 * 512 / 4 + 255) / 256, 256, 0, stream>>>(W2, Whg, Wlg, 1024 * 512 / 4);
    hipMemsetAsync(asrc, 0, 2 * 81920 * sizeof(float), stream);
    gemm_mfma<0><<<dim3(8, rowBlocks), 256, 0, stream>>>(Ahg, Alg, Whg, Wlg, H, nullptr,
                                                         NNODES, 1024, 512, as2, ad2, asrc, adst, 128);
    agg_k<128, 0><<<NNODES, 512, 0, stream>>>(H, nullptr, asrc, adst, rows, esrc, b2, Ahg, Alg, nullptr);

    // ---- layer 3: 1024 -> 8x256 mean; H stored fp16 (40MB ~ L2-resident) ----
    split4_k<<<(2048 * 1024 / 4 + 255) / 256, 256, 0, stream>>>(W3, Whg, Wlg, 2048 * 1024 / 4);
    hipMemsetAsync(asrc, 0, 2 * 81920 * sizeof(float), stream);
    gemm_mfma<1><<<dim3(16, rowBlocks), 256, 0, stream>>>(Ahg, Alg, Whg, Wlg, nullptr, Hh,
                                                          NNODES, 2048, 1024, as3, ad3, asrc, adst, 256);
    agg_k<256, 1><<<NNODES, 512, 0, stream>>>(nullptr, Hh, asrc, adst, rows, esrc, b3, nullptr, nullptr, out);
}

// Round 7
// 483.030 us; speedup vs baseline: 1.4747x; 1.3009x over previous
//
#include <hip/hip_runtime.h>
#include <cstdint>

#define NNODES 10000
#define NEDGES 160000
#define TOT_E  (NEDGES + NNODES)
#define HEADS  8

typedef unsigned short u16;
typedef __attribute__((ext_vector_type(8))) _Float16 h8;   // 8 fp16 in 4 VGPRs (MFMA operand)
typedef __attribute__((ext_vector_type(4))) _Float16 h4;   // 4 fp16 (8B load)
typedef __attribute__((ext_vector_type(4))) float f4;      // MFMA accumulator

__device__ inline u16 f2h(float x) {
    union { _Float16 h; u16 u; } c; c.h = (_Float16)x; return c.u;
}

__device__ inline void gld16(const u16* g, u16* l) {
    __builtin_amdgcn_global_load_lds(
        (const __attribute__((address_space(1))) void*)g,
        (__attribute__((address_space(3))) void*)l, 16, 0, 0);
}

// ---------------- CSR build (dst-sorted) ----------------
__global__ void count_k(const int* __restrict__ ei, int* __restrict__ deg) {
    int i = blockIdx.x * 256 + threadIdx.x;
    if (i >= TOT_E) return;
    int dst = (i < NEDGES) ? ei[NEDGES + i] : (i - NEDGES);
    atomicAdd(deg + dst, 1);
}

__global__ __launch_bounds__(1024) void scan_k(const int* __restrict__ deg,
                                               int* __restrict__ rows) {
    __shared__ int buf[1024];
    int tid = threadIdx.x;
    int base = tid * 10;
    int loc[10]; int s = 0;
    #pragma unroll
    for (int j = 0; j < 10; j++) {
        int i = base + j;
        loc[j] = s;
        s += (i < NNODES) ? deg[i] : 0;
    }
    buf[tid] = s;
    __syncthreads();
    for (int off = 1; off < 1024; off <<= 1) {
        int t = (tid >= off) ? buf[tid - off] : 0;
        __syncthreads();
        buf[tid] += t;
        __syncthreads();
    }
    int ex = tid ? buf[tid - 1] : 0;
    #pragma unroll
    for (int j = 0; j < 10; j++) {
        int i = base + j;
        if (i < NNODES) rows[i] = ex + loc[j];
    }
    if (tid == 1023) rows[NNODES] = buf[1023];
}

__global__ void scatter_k(const int* __restrict__ ei, const int* __restrict__ rows,
                          int* __restrict__ cursor, int* __restrict__ esrc) {
    int i = blockIdx.x * 256 + threadIdx.x;
    if (i >= TOT_E) return;
    int src, dst;
    if (i < NEDGES) { src = ei[i]; dst = ei[NEDGES + i]; }
    else            { src = i - NEDGES; dst = src; }
    int pos = atomicAdd(cursor + dst, 1);
    esrc[rows[dst] + pos] = src;
}

// ---------------- fp32 -> fp16 convert ----------------
__global__ void cvt16_k(const float* __restrict__ in, u16* __restrict__ o, int n4) {
    int i = blockIdx.x * 256 + threadIdx.x;
    if (i >= n4) return;
    float4 v = ((const float4*)in)[i];
    ushort4 h;
    h.x = f2h(v.x); h.y = f2h(v.y); h.z = f2h(v.z); h.w = f2h(v.w);
    ((ushort4*)o)[i] = h;
}

// ---------------- fp16 MFMA GEMM + fused alpha partials ----------------
// C16[M,N] = fp16( A[M,K] * W[N,K]^T ), A/W fp16. 128x128 tile, BK=32, 4 waves
// 2x2 (64x64 each). XOR-swizzled LDS: staging lane fetches global oct
// (lane&3)^((lane>>3)&3); reads xor slot with (l15>>1)&3 -> every
// ds_read_b128 phase is exactly 2-way bank-aliased (free).
// Epilogue: fp16 C store + asrc/adst partials (atomics, pre-zeroed).
__global__ __launch_bounds__(256) void gemm_f16(
    const u16* __restrict__ A, const u16* __restrict__ B,
    u16* __restrict__ C16, int M, int N, int K,
    const float* __restrict__ a_s, const float* __restrict__ a_d,
    float* __restrict__ asrc, float* __restrict__ adst, int Chead)
{
    __shared__ u16 sA[4096], sB[4096];        // 8 KB each
    const int t = threadIdx.x, lane = t & 63, w = t >> 6;
    const int row0 = blockIdx.y * 128, col0 = blockIdx.x * 128;
    const int wm = w & 1, wn = w >> 1;
    const int l15 = lane & 15, quad = lane >> 4;

    // staging: 16 chunks of 16 rows (A:0-7, B:8-15); wave w stages chunks 4w..4w+3
    const int octg = (lane & 3) ^ ((lane >> 3) & 3);    // swizzled global oct
    const int rl   = lane >> 2;                          // row within chunk
    const u16* gp[4]; u16* lp[4];
    #pragma unroll
    for (int q = 0; q < 4; q++) {
        int c = w * 4 + q;
        if (c < 8) {
            int gr = row0 + c * 16 + rl; if (gr >= M) gr = M - 1;
            gp[q] = A + (size_t)gr * K + octg * 8;
            lp[q] = sA + c * 512;
        } else {
            int gc = col0 + (c - 8) * 16 + rl;           // N mult of 128 -> in bounds
            gp[q] = B + (size_t)gc * K + octg * 8;
            lp[q] = sB + (c - 8) * 512;
        }
    }

    // read offsets: row*32 + swizzled-slot*8
    const int sw   = (l15 >> 1) & 3;
    const int aoff = (wm * 64 + l15) * 32 + ((quad ^ sw) * 8);
    const int boff = (wn * 64 + l15) * 32 + ((quad ^ sw) * 8);

    f4 acc[4][4];
    #pragma unroll
    for (int i = 0; i < 4; i++)
        #pragma unroll
        for (int j = 0; j < 4; j++)
            acc[i][j] = (f4){0.f, 0.f, 0.f, 0.f};

    for (int k0 = 0; k0 < K; k0 += 32) {
        #pragma unroll
        for (int q = 0; q < 4; q++) {
            gld16(gp[q], lp[q]);
            gp[q] += 32;
        }
        __syncthreads();   // drains vmcnt before ds_read

        h8 a[4];
        #pragma unroll
        for (int i = 0; i < 4; i++)
            a[i] = *(const h8*)&sA[aoff + i * 512];
        #pragma unroll
        for (int j = 0; j < 4; j++) {
            h8 b = *(const h8*)&sB[boff + j * 512];
            #pragma unroll
            for (int i = 0; i < 4; i++)
                acc[i][j] = __builtin_amdgcn_mfma_f32_16x16x32_f16(a[i], b, acc[i][j], 0, 0, 0);
        }
        __syncthreads();
    }

    // alpha coefficients for this wave's 64-channel span (within one head)
    const int span0 = col0 + wn * 64;
    const int hd = span0 / Chead;
    float av[4], dv[4];
    #pragma unroll
    for (int j = 0; j < 4; j++) {
        av[j] = a_s[span0 + j * 16 + l15];
        dv[j] = a_d[span0 + j * 16 + l15];
    }

    // epilogue: C/D layout col=lane&15, row=quad*4+reg
    #pragma unroll
    for (int i = 0; i < 4; i++) {
        #pragma unroll
        for (int r = 0; r < 4; r++) {
            int gr = row0 + wm * 64 + i * 16 + quad * 4 + r;
            float s1 = 0.f, s2 = 0.f;
            #pragma unroll
            for (int j = 0; j < 4; j++) {
                float v = acc[i][j][r];
                s1 += v * av[j];
                s2 += v * dv[j];
            }
            #pragma unroll
            for (int m = 1; m < 16; m <<= 1) {
                s1 += __shfl_xor(s1, m);
                s2 += __shfl_xor(s2, m);
            }
            if (gr < M) {
                u16* cp = C16 + (size_t)gr * N + span0 + l15;
                #pragma unroll
                for (int j = 0; j < 4; j++)
                    cp[j * 16] = f2h(acc[i][j][r]);
                if (l15 == 0) {
                    atomicAdd(asrc + gr * HEADS + hd, s1);
                    atomicAdd(adst + gr * HEADS + hd, s2);
                }
            }
        }
    }
}

// ---------------- softmax + aggregation ----------------
// One block per node, 8 waves = 8 heads; h gathered as fp16 (all layers).
// No max-subtraction (logits bounded; p/s scale-invariant). LPE = C/4 lanes
// per edge (8B h4 loads), U batched edge-passes in flight.
// MODE 0: concat +bias +ELU -> fp16 plane (next GEMM input).
// MODE 1: LDS head-mean + bias -> fp32 out, coalesced store.
template<int C, int MODE>
__global__ __launch_bounds__(512) void agg_k(const u16* __restrict__ h16,
                                             const float* __restrict__ asrc,
                                             const float* __restrict__ adst,
                                             const int* __restrict__ rows,
                                             const int* __restrict__ esrc,
                                             const float* __restrict__ bias,
                                             u16* __restrict__ oh,
                                             float* __restrict__ outf) {
    constexpr int LPE = C / 4;
    constexpr int EPW = 64 / LPE;
    constexpr int U   = (LPE == 64) ? 16 : (LPE == 32) ? 12 : 8;
    __shared__ float red[MODE == 1 ? HEADS * 256 : 8];

    const int n    = blockIdx.x;
    const int hd   = threadIdx.x >> 6;
    const int lane = threadIdx.x & 63;
    const int sub  = lane / LPE;
    const int cl   = lane % LPE;
    const int beg = rows[n], end = rows[n + 1], deg = end - beg;
    const float ad = adst[n * HEADS + hd];

    float4 acc = {0.f, 0.f, 0.f, 0.f};

    auto gather = [&](int e, float pw, int cdeg) {
        for (int j = 0; j < cdeg; j += EPW * U) {
            int   sn[U]; float wg[U];
            #pragma unroll
            for (int u = 0; u < U; u++) {
                int idx = j + sub + EPW * u;
                int   ss = __shfl(e, idx);
                float ww = __shfl(pw, idx);
                bool ok = idx < cdeg;
                sn[u] = ok ? ss : 0;
                wg[u] = ok ? ww : 0.f;
            }
            h4 v[U];
            #pragma unroll
            for (int u = 0; u < U; u++)
                v[u] = *(const h4*)(h16 + (size_t)sn[u] * (HEADS * C) + hd * C + cl * 4);
            #pragma unroll
            for (int u = 0; u < U; u++) {
                acc.x += wg[u] * (float)v[u].x; acc.y += wg[u] * (float)v[u].y;
                acc.z += wg[u] * (float)v[u].z; acc.w += wg[u] * (float)v[u].w;
            }
        }
    };

    if (deg <= 64) {
        int e = 0; float p = 0.f;
        if (lane < deg) {
            e = esrc[beg + lane];
            float lg = asrc[e * HEADS + hd] + ad;
            lg = (lg > 0.f) ? lg : 0.2f * lg;
            p = __expf(lg);
        }
        float s = p;
        #pragma unroll
        for (int off = 32; off; off >>= 1) s += __shfl_xor(s, off);
        float pw = p / (s + 1e-16f);
        gather(e, pw, deg);
    } else {
        float ssum = 0.f;
        for (int i = beg + lane; i < end; i += 64) {
            float lg = asrc[esrc[i] * HEADS + hd] + ad;
            lg = (lg > 0.f) ? lg : 0.2f * lg;
            ssum += __expf(lg);
        }
        #pragma unroll
        for (int off = 32; off; off >>= 1) ssum += __shfl_xor(ssum, off);
        float inv = 1.f / (ssum + 1e-16f);
        for (int c0 = beg; c0 < end; c0 += 64) {
            int cdeg = min(64, end - c0);
            int e = 0; float pw = 0.f;
            if (lane < cdeg) {
                e = esrc[c0 + lane];
                float lg = asrc[e * HEADS + hd] + ad;
                lg = (lg > 0.f) ? lg : 0.2f * lg;
                pw = __expf(lg) * inv;
            }
            gather(e, pw, cdeg);
        }
    }

    #pragma unroll
    for (int m = LPE; m < 64; m <<= 1) {
        acc.x += __shfl_xor(acc.x, m); acc.y += __shfl_xor(acc.y, m);
        acc.z += __shfl_xor(acc.z, m); acc.w += __shfl_xor(acc.w, m);
    }

    if constexpr (MODE == 0) {
        if (sub == 0) {
            const float* bp = bias + hd * C + cl * 4;
            float4 b = *(const float4*)bp;
            float r[4] = {acc.x + b.x, acc.y + b.y, acc.z + b.z, acc.w + b.w};
            #pragma unroll
            for (int j = 0; j < 4; j++)
                r[j] = (r[j] > 0.f) ? r[j] : (expf(r[j]) - 1.f);   // ELU
            ushort4 hv;
            hv.x = f2h(r[0]); hv.y = f2h(r[1]); hv.z = f2h(r[2]); hv.w = f2h(r[3]);
            *(ushort4*)(oh + (size_t)n * (HEADS * C) + hd * C + cl * 4) = hv;
        }
    } else {
        *(float4*)&red[hd * 256 + lane * 4] = acc;
        __syncthreads();
        int tid = threadIdx.x;
        if (tid < 256) {
            float s = 0.f;
            #pragma unroll
            for (int hh = 0; hh < HEADS; hh++) s += red[hh * 256 + tid];
            outf[(size_t)n * 256 + tid] = s * 0.125f + bias[tid];
        }
    }
}

// ---------------- launch ----------------
extern "C" void kernel_launch(void* const* d_in, const int* in_sizes, int n_in,
                              void* d_out, int out_size, void* d_ws, size_t ws_size,
                              hipStream_t stream) {
    const float* x   = (const float*)d_in[0];
    const int*   ei  = (const int*)d_in[1];
    const float* W1  = (const float*)d_in[2];
    const float* as1 = (const float*)d_in[3];
    const float* ad1 = (const float*)d_in[4];
    const float* b1  = (const float*)d_in[5];
    const float* W2  = (const float*)d_in[6];
    const float* as2 = (const float*)d_in[7];
    const float* ad2 = (const float*)d_in[8];
    const float* b2  = (const float*)d_in[9];
    const float* W3  = (const float*)d_in[10];
    const float* as3 = (const float*)d_in[11];
    const float* ad3 = (const float*)d_in[12];
    const float* b3  = (const float*)d_in[13];
    float* out = (float*)d_out;

    int* deg    = (int*)d_ws;
    int* cursor = deg + 10240;
    int* rows   = cursor + 10240;
    int* esrc   = rows + 10240;
    float* asrc = (float*)(esrc + 170240);   // 81920 floats
    float* adst = asrc + 81920;              // 81920 floats (contiguous)
    u16* Hh     = (u16*)(adst + 81920);      // fp16 h, up to 10000*2048
    u16* Af     = Hh + (size_t)NNODES * 2048;   // fp16 GEMM input, up to 10000*1024
    u16* Wf     = Af + (size_t)NNODES * 1024;   // fp16 weights, up to 2048*1024

    hipMemsetAsync(deg, 0, 2 * 10240 * sizeof(int), stream);

    count_k<<<(TOT_E + 255) / 256, 256, 0, stream>>>(ei, deg);
    scan_k<<<1, 1024, 0, stream>>>(deg, rows);
    scatter_k<<<(TOT_E + 255) / 256, 256, 0, stream>>>(ei, rows, cursor, esrc);

    const int rowBlocks = (NNODES + 127) / 128;   // 79

    // ---- layer 1: IN=256 -> 8x64 concat ----
    cvt16_k<<<(NNODES * 256 / 4 + 255) / 256, 256, 0, stream>>>(x, Af, NNODES * 256 / 4);
    cvt16_k<<<(512 * 256 / 4 + 255) / 256, 256, 0, stream>>>(W1, Wf, 512 * 256 / 4);
    hipMemsetAsync(asrc, 0, 2 * 81920 * sizeof(float), stream);
    gemm_f16<<<dim3(4, rowBlocks), 256, 0, stream>>>(Af, Wf, Hh, NNODES, 512, 256,
                                                     as1, ad1, asrc, adst, 64);
    agg_k<64, 0><<<NNODES, 512, 0, stream>>>(Hh, asrc, adst, rows, esrc, b1, Af, nullptr);

    // ---- layer 2: 512 -> 8x128 concat ----
    cvt16_k<<<(1024 * 512 / 4 + 255) / 256, 256, 0, stream>>>(W2, Wf, 1024 * 512 / 4);
    hipMemsetAsync(asrc, 0, 2 * 81920 * sizeof(float), stream);
    gemm_f16<<<dim3(8, rowBlocks), 256, 0, stream>>>(Af, Wf, Hh, NNODES, 1024, 512,
                                                     as2, ad2, asrc, adst, 128);
    agg_k<128, 0><<<NNODES, 512, 0, stream>>>(Hh, asrc, adst, rows, esrc, b2, Af, nullptr);

    // ---- layer 3: 1024 -> 8x256 mean ----
    cvt16_k<<<(2048 * 1024 / 4 + 255) / 256, 256, 0, stream>>>(W3, Wf, 2048 * 1024 / 4);
    hipMemsetAsync(asrc, 0, 2 * 81920 * sizeof(float), stream);
    gemm_f16<<<dim3(16, rowBlocks), 256, 0, stream>>>(Af, Wf, Hh, NNODES, 2048, 1024,
                                                      as3, ad3, asrc, adst, 256);
    agg_k<256, 1><<<NNODES, 512, 0, stream>>>(Hh, asrc, adst, rows, esrc, b3, nullptr, out);
}

// Round 9
// 473.243 us; speedup vs baseline: 1.5052x; 1.0207x over previous
//
#include <hip/hip_runtime.h>
#include <cstdint>

#define NNODES 10000
#define NEDGES 160000
#define TOT_E  (NEDGES + NNODES)
#define HEADS  8

typedef unsigned short u16;
typedef __attribute__((ext_vector_type(8))) _Float16 h8;   // 8 fp16 in 4 VGPRs (MFMA operand)
typedef __attribute__((ext_vector_type(4))) _Float16 h4;   // 4 fp16 (8B load)
typedef __attribute__((ext_vector_type(4))) float f4;      // MFMA accumulator

__device__ inline u16 f2h(float x) {
    union { _Float16 h; u16 u; } c; c.h = (_Float16)x; return c.u;
}

__device__ inline void gld16(const u16* g, u16* l) {
    __builtin_amdgcn_global_load_lds(
        (const __attribute__((address_space(1))) void*)g,
        (__attribute__((address_space(3))) void*)l, 16, 0, 0);
}

// ---------------- CSR build (dst-sorted) ----------------
__global__ void count_k(const int* __restrict__ ei, int* __restrict__ deg) {
    int i = blockIdx.x * 256 + threadIdx.x;
    if (i >= TOT_E) return;
    int dst = (i < NEDGES) ? ei[NEDGES + i] : (i - NEDGES);
    atomicAdd(deg + dst, 1);
}

__global__ __launch_bounds__(1024) void scan_k(const int* __restrict__ deg,
                                               int* __restrict__ rows) {
    __shared__ int buf[1024];
    int tid = threadIdx.x;
    int base = tid * 10;
    int loc[10]; int s = 0;
    #pragma unroll
    for (int j = 0; j < 10; j++) {
        int i = base + j;
        loc[j] = s;
        s += (i < NNODES) ? deg[i] : 0;
    }
    buf[tid] = s;
    __syncthreads();
    for (int off = 1; off < 1024; off <<= 1) {
        int t = (tid >= off) ? buf[tid - off] : 0;
        __syncthreads();
        buf[tid] += t;
        __syncthreads();
    }
    int ex = tid ? buf[tid - 1] : 0;
    #pragma unroll
    for (int j = 0; j < 10; j++) {
        int i = base + j;
        if (i < NNODES) rows[i] = ex + loc[j];
    }
    if (tid == 1023) rows[NNODES] = buf[1023];
}

__global__ void scatter_k(const int* __restrict__ ei, const int* __restrict__ rows,
                          int* __restrict__ cursor, int* __restrict__ esrc) {
    int i = blockIdx.x * 256 + threadIdx.x;
    if (i >= TOT_E) return;
    int src, dst;
    if (i < NEDGES) { src = ei[i]; dst = ei[NEDGES + i]; }
    else            { src = i - NEDGES; dst = src; }
    int pos = atomicAdd(cursor + dst, 1);
    esrc[rows[dst] + pos] = src;
}

// ---------------- fp32 -> fp16 convert ----------------
__global__ void cvt16_k(const float* __restrict__ in, u16* __restrict__ o, int n4) {
    int i = blockIdx.x * 256 + threadIdx.x;
    if (i >= n4) return;
    float4 v = ((const float4*)in)[i];
    ushort4 h;
    h.x = f2h(v.x); h.y = f2h(v.y); h.z = f2h(v.z); h.w = f2h(v.w);
    ((ushort4*)o)[i] = h;
}

// ---------------- fp16 MFMA GEMM + fused alpha partials ----------------
// C16[M,N] = fp16( A[M,K] * W[N,K]^T ), A/W fp16. 128x128 tile, BK=64 (16 KB
// sA + 16 KB sB), 4 waves 2x2 (64x64 each), 32 MFMA per wave per barrier.
// XOR-swizzled LDS (8 octs): staging lane fetches global oct
// (lane&7)^(lane>>3); reads use oct (s*4+quad)^(l15&7) -> every ds_read_b128
// phase covers all 32 banks at 2-way aliasing (free, m136).
// RACE FIX (r8 post-timing divergence): __syncthreads() only guarantees
// lgkmcnt drain; the vmcnt(0) drain for global_load_lds->LDS writes is
// compiler-alias-analysis dependent. Force it explicitly before the barrier.
__global__ __launch_bounds__(256) void gemm_f16(
    const u16* __restrict__ A, const u16* __restrict__ B,
    u16* __restrict__ C16, int M, int N, int K,
    const float* __restrict__ a_s, const float* __restrict__ a_d,
    float* __restrict__ asrc, float* __restrict__ adst, int Chead)
{
    __shared__ u16 sA[8192], sB[8192];        // 16 KB each: 128 rows x 64 cols
    const int t = threadIdx.x, lane = t & 63, w = t >> 6;
    const int row0 = blockIdx.y * 128, col0 = blockIdx.x * 128;
    const int wm = w & 1, wn = w >> 1;
    const int l15 = lane & 15, quad = lane >> 4;

    // staging: 32 chunks of 8 rows x 64 cols (1 KB each); A: c=0..15, B: c=16..31.
    // wave w stages chunks 8w..8w+7. lane covers row lane>>3, swizzled oct
    // (lane&7)^(lane>>3); HW places lane's 16B at chunkbase + lane*16.
    const int octg = (lane & 7) ^ (lane >> 3);
    const int rl   = lane >> 3;     // 0..7
    const u16* gp[8]; u16* lp[8];
    #pragma unroll
    for (int q = 0; q < 8; q++) {
        int c = w * 8 + q;
        if (c < 16) {
            int gr = row0 + c * 8 + rl; if (gr >= M) gr = M - 1;
            gp[q] = A + (size_t)gr * K + octg * 8;
            lp[q] = sA + c * 512;
        } else {
            int gc = col0 + (c - 16) * 8 + rl;    // N mult of 128 -> in bounds
            gp[q] = B + (size_t)gc * K + octg * 8;
            lp[q] = sB + (c - 16) * 512;
        }
    }

    const int swz = (l15 & 7);

    f4 acc[4][4];
    #pragma unroll
    for (int i = 0; i < 4; i++)
        #pragma unroll
        for (int j = 0; j < 4; j++)
            acc[i][j] = (f4){0.f, 0.f, 0.f, 0.f};

    for (int k0 = 0; k0 < K; k0 += 64) {
        #pragma unroll
        for (int q = 0; q < 8; q++) {
            gld16(gp[q], lp[q]);
            gp[q] += 64;
        }
        __builtin_amdgcn_s_waitcnt(0);   // vmcnt(0): gld16 LDS writes landed
        __syncthreads();

        #pragma unroll
        for (int s = 0; s < 2; s++) {
            const int po = ((s * 4 + quad) ^ swz) * 8;   // swizzled physical oct
            h8 a[4];
            #pragma unroll
            for (int i = 0; i < 4; i++)
                a[i] = *(const h8*)&sA[(wm * 64 + i * 16 + l15) * 64 + po];
            #pragma unroll
            for (int j = 0; j < 4; j++) {
                h8 b = *(const h8*)&sB[(wn * 64 + j * 16 + l15) * 64 + po];
                #pragma unroll
                for (int i = 0; i < 4; i++)
                    acc[i][j] = __builtin_amdgcn_mfma_f32_16x16x32_f16(a[i], b, acc[i][j], 0, 0, 0);
            }
        }
        __syncthreads();
    }

    // alpha coefficients for this wave's 64-channel span (within one head)
    const int span0 = col0 + wn * 64;
    const int hd = span0 / Chead;
    float av[4], dv[4];
    #pragma unroll
    for (int j = 0; j < 4; j++) {
        av[j] = a_s[span0 + j * 16 + l15];
        dv[j] = a_d[span0 + j * 16 + l15];
    }

    // epilogue: C/D layout col=lane&15, row=quad*4+reg
    #pragma unroll
    for (int i = 0; i < 4; i++) {
        #pragma unroll
        for (int r = 0; r < 4; r++) {
            int gr = row0 + wm * 64 + i * 16 + quad * 4 + r;
            float s1 = 0.f, s2 = 0.f;
            #pragma unroll
            for (int j = 0; j < 4; j++) {
                float v = acc[i][j][r];
                s1 += v * av[j];
                s2 += v * dv[j];
            }
            #pragma unroll
            for (int m = 1; m < 16; m <<= 1) {
                s1 += __shfl_xor(s1, m);
                s2 += __shfl_xor(s2, m);
            }
            if (gr < M) {
                u16* cp = C16 + (size_t)gr * N + span0 + l15;
                #pragma unroll
                for (int j = 0; j < 4; j++)
                    cp[j * 16] = f2h(acc[i][j][r]);
                if (l15 == 0) {
                    atomicAdd(asrc + gr * HEADS + hd, s1);
                    atomicAdd(adst + gr * HEADS + hd, s2);
                }
            }
        }
    }
}

// ---------------- softmax + aggregation ----------------
// One block per node, 8 waves = 8 heads; h gathered as fp16 (all layers).
// No max-subtraction (logits bounded; p/s scale-invariant). LPE = C/4 lanes
// per edge (8B h4 loads), U batched edge-passes in flight.
// MODE 0: concat +bias +ELU -> fp16 plane (next GEMM input).
// MODE 1: LDS head-mean + bias -> fp32 out, coalesced store.
template<int C, int MODE>
__global__ __launch_bounds__(512) void agg_k(const u16* __restrict__ h16,
                                             const float* __restrict__ asrc,
                                             const float* __restrict__ adst,
                                             const int* __restrict__ rows,
                                             const int* __restrict__ esrc,
                                             const float* __restrict__ bias,
                                             u16* __restrict__ oh,
                                             float* __restrict__ outf) {
    constexpr int LPE = C / 4;
    constexpr int EPW = 64 / LPE;
    constexpr int U   = (LPE == 64) ? 16 : (LPE == 32) ? 12 : 8;
    __shared__ float red[MODE == 1 ? HEADS * 256 : 8];

    const int n    = blockIdx.x;
    const int hd   = threadIdx.x >> 6;
    const int lane = threadIdx.x & 63;
    const int sub  = lane / LPE;
    const int cl   = lane % LPE;
    const int beg = rows[n], end = rows[n + 1], deg = end - beg;
    const float ad = adst[n * HEADS + hd];

    float4 acc = {0.f, 0.f, 0.f, 0.f};

    auto gather = [&](int e, float pw, int cdeg) {
        for (int j = 0; j < cdeg; j += EPW * U) {
            int   sn[U]; float wg[U];
            #pragma unroll
            for (int u = 0; u < U; u++) {
                int idx = j + sub + EPW * u;
                int   ss = __shfl(e, idx);
                float ww = __shfl(pw, idx);
                bool ok = idx < cdeg;
                sn[u] = ok ? ss : 0;
                wg[u] = ok ? ww : 0.f;
            }
            h4 v[U];
            #pragma unroll
            for (int u = 0; u < U; u++)
                v[u] = *(const h4*)(h16 + (size_t)sn[u] * (HEADS * C) + hd * C + cl * 4);
            #pragma unroll
            for (int u = 0; u < U; u++) {
                acc.x += wg[u] * (float)v[u].x; acc.y += wg[u] * (float)v[u].y;
                acc.z += wg[u] * (float)v[u].z; acc.w += wg[u] * (float)v[u].w;
            }
        }
    };

    if (deg <= 64) {
        int e = 0; float p = 0.f;
        if (lane < deg) {
            e = esrc[beg + lane];
            float lg = asrc[e * HEADS + hd] + ad;
            lg = (lg > 0.f) ? lg : 0.2f * lg;
            p = __expf(lg);
        }
        float s = p;
        #pragma unroll
        for (int off = 32; off; off >>= 1) s += __shfl_xor(s, off);
        float pw = p / (s + 1e-16f);
        gather(e, pw, deg);
    } else {
        float ssum = 0.f;
        for (int i = beg + lane; i < end; i += 64) {
            float lg = asrc[esrc[i] * HEADS + hd] + ad;
            lg = (lg > 0.f) ? lg : 0.2f * lg;
            ssum += __expf(lg);
        }
        #pragma unroll
        for (int off = 32; off; off >>= 1) ssum += __shfl_xor(ssum, off);
        float inv = 1.f / (ssum + 1e-16f);
        for (int c0 = beg; c0 < end; c0 += 64) {
            int cdeg = min(64, end - c0);
            int e = 0; float pw = 0.f;
            if (lane < cdeg) {
                e = esrc[c0 + lane];
                float lg = asrc[e * HEADS + hd] + ad;
                lg = (lg > 0.f) ? lg : 0.2f * lg;
                pw = __expf(lg) * inv;
            }
            gather(e, pw, cdeg);
        }
    }

    #pragma unroll
    for (int m = LPE; m < 64; m <<= 1) {
        acc.x += __shfl_xor(acc.x, m); acc.y += __shfl_xor(acc.y, m);
        acc.z += __shfl_xor(acc.z, m); acc.w += __shfl_xor(acc.w, m);
    }

    if constexpr (MODE == 0) {
        if (sub == 0) {
            const float* bp = bias + hd * C + cl * 4;
            float4 b = *(const float4*)bp;
            float r[4] = {acc.x + b.x, acc.y + b.y, acc.z + b.z, acc.w + b.w};
            #pragma unroll
            for (int j = 0; j < 4; j++)
                r[j] = (r[j] > 0.f) ? r[j] : (expf(r[j]) - 1.f);   // ELU
            ushort4 hv;
            hv.x = f2h(r[0]); hv.y = f2h(r[1]); hv.z = f2h(r[2]); hv.w = f2h(r[3]);
            *(ushort4*)(oh + (size_t)n * (HEADS * C) + hd * C + cl * 4) = hv;
        }
    } else {
        *(float4*)&red[hd * 256 + lane * 4] = acc;
        __syncthreads();
        int tid = threadIdx.x;
        if (tid < 256) {
            float s = 0.f;
            #pragma unroll
            for (int hh = 0; hh < HEADS; hh++) s += red[hh * 256 + tid];
            outf[(size_t)n * 256 + tid] = s * 0.125f + bias[tid];
        }
    }
}

// ---------------- launch ----------------
extern "C" void kernel_launch(void* const* d_in, const int* in_sizes, int n_in,
                              void* d_out, int out_size, void* d_ws, size_t ws_size,
                              hipStream_t stream) {
    const float* x   = (const float*)d_in[0];
    const int*   ei  = (const int*)d_in[1];
    const float* W1  = (const float*)d_in[2];
    const float* as1 = (const float*)d_in[3];
    const float* ad1 = (const float*)d_in[4];
    const float* b1  = (const float*)d_in[5];
    const float* W2  = (const float*)d_in[6];
    const float* as2 = (const float*)d_in[7];
    const float* ad2 = (const float*)d_in[8];
    const float* b2  = (const float*)d_in[9];
    const float* W3  = (const float*)d_in[10];
    const float* as3 = (const float*)d_in[11];
    const float* ad3 = (const float*)d_in[12];
    const float* b3  = (const float*)d_in[13];
    float* out = (float*)d_out;

    int* deg    = (int*)d_ws;
    int* cursor = deg + 10240;
    int* rows   = cursor + 10240;
    int* esrc   = rows + 10240;
    float* asrc = (float*)(esrc + 170240);   // 81920 floats
    float* adst = asrc + 81920;              // 81920 floats (contiguous)
    u16* Hh     = (u16*)(adst + 81920);      // fp16 h, up to 10000*2048
    u16* Af     = Hh + (size_t)NNODES * 2048;   // fp16 GEMM input, up to 10000*1024
    u16* Wf     = Af + (size_t)NNODES * 1024;   // fp16 weights, up to 2048*1024

    hipMemsetAsync(deg, 0, 2 * 10240 * sizeof(int), stream);

    count_k<<<(TOT_E + 255) / 256, 256, 0, stream>>>(ei, deg);
    scan_k<<<1, 1024, 0, stream>>>(deg, rows);
    scatter_k<<<(TOT_E + 255) / 256, 256, 0, stream>>>(ei, rows, cursor, esrc);

    const int rowBlocks = (NNODES + 127) / 128;   // 79

    // ---- layer 1: IN=256 -> 8x64 concat ----
    cvt16_k<<<(NNODES * 256 / 4 + 255) / 256, 256, 0, stream>>>(x, Af, NNODES * 256 / 4);
    cvt16_k<<<(512 * 256 / 4 + 255) / 256, 256, 0, stream>>>(W1, Wf, 512 * 256 / 4);
    hipMemsetAsync(asrc, 0, 2 * 81920 * sizeof(float), stream);
    gemm_f16<<<dim3(4, rowBlocks), 256, 0, stream>>>(Af, Wf, Hh, NNODES, 512, 256,
                                                     as1, ad1, asrc, adst, 64);
    agg_k<64, 0><<<NNODES, 512, 0, stream>>>(Hh, asrc, adst, rows, esrc, b1, Af, nullptr);

    // ---- layer 2: 512 -> 8x128 concat ----
    cvt16_k<<<(1024 * 512 / 4 + 255) / 256, 256, 0, stream>>>(W2, Wf, 1024 * 512 / 4);
    hipMemsetAsync(asrc, 0, 2 * 81920 * sizeof(float), stream);
    gemm_f16<<<dim3(8, rowBlocks), 256, 0, stream>>>(Af, Wf, Hh, NNODES, 1024, 512,
                                                     as2, ad2, asrc, adst, 128);
    agg_k<128, 0><<<NNODES, 512, 0, stream>>>(Hh, asrc, adst, rows, esrc, b2, Af, nullptr);

    // ---- layer 3: 1024 -> 8x256 mean ----
    cvt16_k<<<(2048 * 1024 / 4 + 255) / 256, 256, 0, stream>>>(W3, Wf, 2048 * 1024 / 4);
    hipMemsetAsync(asrc, 0, 2 * 81920 * sizeof(float), stream);
    gemm_f16<<<dim3(16, rowBlocks), 256, 0, stream>>>(Af, Wf, Hh, NNODES, 2048, 1024,
                                                      as3, ad3, asrc, adst, 256);
    agg_k<256, 1><<<NNODES, 512, 0, stream>>>(Hh, asrc, adst, rows, esrc, b3, nullptr, out);
}

// Round 10
// 469.198 us; speedup vs baseline: 1.5181x; 1.0086x over previous
//
#include <hip/hip_runtime.h>
#include <cstdint>

#define NNODES 10000
#define NEDGES 160000
#define TOT_E  (NEDGES + NNODES)
#define HEADS  8

typedef unsigned short u16;
typedef __attribute__((ext_vector_type(8))) _Float16 h8;   // 8 fp16 (16B)
typedef __attribute__((ext_vector_type(4))) _Float16 h4;   // 4 fp16 (8B)
typedef __attribute__((ext_vector_type(4))) float f4;      // MFMA accumulator

// s_waitcnt imm: [3:0] vmcnt_lo, [6:4] expcnt, [11:8] lgkmcnt, [15:14] vmcnt_hi
#define WAIT_VM(n) __builtin_amdgcn_s_waitcnt(0x0F70 | (n))   // vmcnt(n), lgkm/exp no-wait

__device__ inline u16 f2h(float x) {
    union { _Float16 h; u16 u; } c; c.h = (_Float16)x; return c.u;
}

__device__ inline void gld16(const u16* g, u16* l) {
    __builtin_amdgcn_global_load_lds(
        (const __attribute__((address_space(1))) void*)g,
        (__attribute__((address_space(3))) void*)l, 16, 0, 0);
}

// ---------------- CSR build (dst-sorted) ----------------
__global__ void count_k(const int* __restrict__ ei, int* __restrict__ deg) {
    int i = blockIdx.x * 256 + threadIdx.x;
    if (i >= TOT_E) return;
    int dst = (i < NEDGES) ? ei[NEDGES + i] : (i - NEDGES);
    atomicAdd(deg + dst, 1);
}

__global__ __launch_bounds__(1024) void scan_k(const int* __restrict__ deg,
                                               int* __restrict__ rows) {
    __shared__ int buf[1024];
    int tid = threadIdx.x;
    int base = tid * 10;
    int loc[10]; int s = 0;
    #pragma unroll
    for (int j = 0; j < 10; j++) {
        int i = base + j;
        loc[j] = s;
        s += (i < NNODES) ? deg[i] : 0;
    }
    buf[tid] = s;
    __syncthreads();
    for (int off = 1; off < 1024; off <<= 1) {
        int t = (tid >= off) ? buf[tid - off] : 0;
        __syncthreads();
        buf[tid] += t;
        __syncthreads();
    }
    int ex = tid ? buf[tid - 1] : 0;
    #pragma unroll
    for (int j = 0; j < 10; j++) {
        int i = base + j;
        if (i < NNODES) rows[i] = ex + loc[j];
    }
    if (tid == 1023) rows[NNODES] = buf[1023];
}

__global__ void scatter_k(const int* __restrict__ ei, const int* __restrict__ rows,
                          int* __restrict__ cursor, int* __restrict__ esrc) {
    int i = blockIdx.x * 256 + threadIdx.x;
    if (i >= TOT_E) return;
    int src, dst;
    if (i < NEDGES) { src = ei[i]; dst = ei[NEDGES + i]; }
    else            { src = i - NEDGES; dst = src; }
    int pos = atomicAdd(cursor + dst, 1);
    esrc[rows[dst] + pos] = src;
}

// ---------------- fp32 -> fp16 convert ----------------
__global__ void cvt16_k(const float* __restrict__ in, u16* __restrict__ o, int n4) {
    int i = blockIdx.x * 256 + threadIdx.x;
    if (i >= n4) return;
    float4 v = ((const float4*)in)[i];
    ushort4 h;
    h.x = f2h(v.x); h.y = f2h(v.y); h.z = f2h(v.z); h.w = f2h(v.w);
    ((ushort4*)o)[i] = h;
}

// ---------------- fp16 MFMA GEMM, double-buffered LDS ----------------
// C16[M,N] = fp16( A[M,K] * W[N,K]^T ). 128x128 tile, BK=32, 2 LDS buffers
// (2 x 16 KB). K-loop: prefetch tile k+1 -> s_waitcnt vmcnt(4) (tile k landed,
// prefetch stays in flight) -> RAW s_barrier (no compiler vmcnt(0) drain) ->
// 16 MFMA from tile k -> raw barrier (readers done before overwrite).
// 4-oct XOR swizzle (r7-verified): stage oct (lane&3)^((lane>>3)&3), read oct
// (quad^((l15>>1)&3)) -> conflict-free ds_read_b128.
// Epilogue: fp16 C store + fused asrc/adst alpha partials (atomics, pre-zeroed).
__global__ __launch_bounds__(256) void gemm_f16(
    const u16* __restrict__ A, const u16* __restrict__ B,
    u16* __restrict__ C16, int M, int N, int K,
    const float* __restrict__ a_s, const float* __restrict__ a_d,
    float* __restrict__ asrc, float* __restrict__ adst, int Chead)
{
    __shared__ u16 sh[2][8192];               // [buf][A:0..4095 | B:4096..8191]
    const int t = threadIdx.x, lane = t & 63, w = t >> 6;
    const int row0 = blockIdx.y * 128, col0 = blockIdx.x * 128;
    const int wm = w & 1, wn = w >> 1;
    const int l15 = lane & 15, quad = lane >> 4;

    // staging: 16 chunks of 16 rows x 32 cols (1 KB); A: c=0..7, B: c=8..15.
    // wave w stages chunks 4w..4w+3; lane = row (lane>>2), swizzled oct.
    const int octg = (lane & 3) ^ ((lane >> 3) & 3);
    const int rl   = lane >> 2;               // 0..15
    const u16* gp[4]; int lofs[4];
    #pragma unroll
    for (int q = 0; q < 4; q++) {
        int c = w * 4 + q;
        if (c < 8) {
            int gr = row0 + c * 16 + rl; if (gr >= M) gr = M - 1;
            gp[q] = A + (size_t)gr * K + octg * 8;
            lofs[q] = c * 512;
        } else {
            int gc = col0 + (c - 8) * 16 + rl;    // N mult of 128 -> in bounds
            gp[q] = B + (size_t)gc * K + octg * 8;
            lofs[q] = 4096 + (c - 8) * 512;
        }
    }

    const int sw = (l15 >> 1) & 3;
    const int po = (quad ^ sw) * 8;           // swizzled physical oct (read)
    const int arow = (wm * 64 + l15) * 32;
    const int brow = 4096 + (wn * 64 + l15) * 32;

    f4 acc[4][4];
    #pragma unroll
    for (int i = 0; i < 4; i++)
        #pragma unroll
        for (int j = 0; j < 4; j++)
            acc[i][j] = (f4){0.f, 0.f, 0.f, 0.f};

    const int T = K >> 5;

    // prologue: stage tile 0 into buf 0
    #pragma unroll
    for (int q = 0; q < 4; q++) { gld16(gp[q], &sh[0][lofs[q]]); gp[q] += 32; }

    for (int k = 0; k < T; k++) {
        const int p = k & 1;
        if (k + 1 < T) {
            #pragma unroll
            for (int q = 0; q < 4; q++) { gld16(gp[q], &sh[1 - p][lofs[q]]); gp[q] += 32; }
            WAIT_VM(4);                       // tile k's 4 loads landed; prefetch in flight
        } else {
            WAIT_VM(0);
        }
        __builtin_amdgcn_s_barrier();         // raw: no compiler vmcnt(0) drain

        const u16* sa = &sh[p][0];
        h8 a[4];
        #pragma unroll
        for (int i = 0; i < 4; i++)
            a[i] = *(const h8*)&sa[arow + i * 512 + po];
        #pragma unroll
        for (int j = 0; j < 4; j++) {
            h8 b = *(const h8*)&sa[brow + j * 512 + po];
            #pragma unroll
            for (int i = 0; i < 4; i++)
                acc[i][j] = __builtin_amdgcn_mfma_f32_16x16x32_f16(a[i], b, acc[i][j], 0, 0, 0);
        }
        __builtin_amdgcn_s_barrier();         // all reads done before buf overwrite
    }

    // alpha coefficients for this wave's 64-channel span (within one head)
    const int span0 = col0 + wn * 64;
    const int hd = span0 / Chead;
    float av[4], dv[4];
    #pragma unroll
    for (int j = 0; j < 4; j++) {
        av[j] = a_s[span0 + j * 16 + l15];
        dv[j] = a_d[span0 + j * 16 + l15];
    }

    // epilogue: C/D layout col=lane&15, row=quad*4+reg
    #pragma unroll
    for (int i = 0; i < 4; i++) {
        #pragma unroll
        for (int r = 0; r < 4; r++) {
            int gr = row0 + wm * 64 + i * 16 + quad * 4 + r;
            float s1 = 0.f, s2 = 0.f;
            #pragma unroll
            for (int j = 0; j < 4; j++) {
                float v = acc[i][j][r];
                s1 += v * av[j];
                s2 += v * dv[j];
            }
            #pragma unroll
            for (int m = 1; m < 16; m <<= 1) {
                s1 += __shfl_xor(s1, m);
                s2 += __shfl_xor(s2, m);
            }
            if (gr < M) {
                u16* cp = C16 + (size_t)gr * N + span0 + l15;
                #pragma unroll
                for (int j = 0; j < 4; j++)
                    cp[j * 16] = f2h(acc[i][j][r]);
                if (l15 == 0) {
                    atomicAdd(asrc + gr * HEADS + hd, s1);
                    atomicAdd(adst + gr * HEADS + hd, s2);
                }
            }
        }
    }
}

// ---------------- softmax + aggregation ----------------
// One block per node, 8 waves = 8 heads; h gathered as fp16.
// C=256 (layer 3): VEC=8 -> 16B h8 gathers, LPE=32. C=64/128: VEC=4 (8B h4).
// No max-subtraction (logits bounded; p/s scale-invariant).
// MODE 0: concat +bias +ELU -> fp16 plane. MODE 1: LDS head-mean + bias.
template<int C, int MODE>
__global__ __launch_bounds__(512) void agg_k(const u16* __restrict__ h16,
                                             const float* __restrict__ asrc,
                                             const float* __restrict__ adst,
                                             const int* __restrict__ rows,
                                             const int* __restrict__ esrc,
                                             const float* __restrict__ bias,
                                             u16* __restrict__ oh,
                                             float* __restrict__ outf) {
    constexpr int VEC = (C == 256) ? 8 : 4;
    constexpr int LPE = C / VEC;
    constexpr int EPW = 64 / LPE;
    constexpr int U   = (VEC == 8) ? 8 : ((LPE == 32) ? 12 : 8);
    __shared__ float red[MODE == 1 ? HEADS * 256 : 8];

    const int n    = blockIdx.x;
    const int hd   = threadIdx.x >> 6;
    const int lane = threadIdx.x & 63;
    const int sub  = lane / LPE;
    const int cl   = lane % LPE;
    const int beg = rows[n], end = rows[n + 1], deg = end - beg;
    const float ad = adst[n * HEADS + hd];

    float acc[VEC] = {};

    auto gather = [&](int e, float pw, int cdeg) {
        for (int j = 0; j < cdeg; j += EPW * U) {
            int   sn[U]; float wg[U];
            #pragma unroll
            for (int u = 0; u < U; u++) {
                int idx = j + sub + EPW * u;
                int   ss = __shfl(e, idx);
                float ww = __shfl(pw, idx);
                bool ok = idx < cdeg;
                sn[u] = ok ? ss : 0;
                wg[u] = ok ? ww : 0.f;
            }
            if constexpr (VEC == 8) {
                h8 v[U];
                #pragma unroll
                for (int u = 0; u < U; u++)
                    v[u] = *(const h8*)(h16 + (size_t)sn[u] * (HEADS * C) + hd * C + cl * 8);
                #pragma unroll
                for (int u = 0; u < U; u++)
                    #pragma unroll
                    for (int i = 0; i < 8; i++)
                        acc[i] += wg[u] * (float)v[u][i];
            } else {
                h4 v[U];
                #pragma unroll
                for (int u = 0; u < U; u++)
                    v[u] = *(const h4*)(h16 + (size_t)sn[u] * (HEADS * C) + hd * C + cl * 4);
                #pragma unroll
                for (int u = 0; u < U; u++)
                    #pragma unroll
                    for (int i = 0; i < 4; i++)
                        acc[i] += wg[u] * (float)v[u][i];
            }
        }
    };

    if (deg <= 64) {
        int e = 0; float p = 0.f;
        if (lane < deg) {
            e = esrc[beg + lane];
            float lg = asrc[e * HEADS + hd] + ad;
            lg = (lg > 0.f) ? lg : 0.2f * lg;
            p = __expf(lg);
        }
        float s = p;
        #pragma unroll
        for (int off = 32; off; off >>= 1) s += __shfl_xor(s, off);
        float pw = p / (s + 1e-16f);
        gather(e, pw, deg);
    } else {
        float ssum = 0.f;
        for (int i = beg + lane; i < end; i += 64) {
            float lg = asrc[esrc[i] * HEADS + hd] + ad;
            lg = (lg > 0.f) ? lg : 0.2f * lg;
            ssum += __expf(lg);
        }
        #pragma unroll
        for (int off = 32; off; off >>= 1) ssum += __shfl_xor(ssum, off);
        float inv = 1.f / (ssum + 1e-16f);
        for (int c0 = beg; c0 < end; c0 += 64) {
            int cdeg = min(64, end - c0);
            int e = 0; float pw = 0.f;
            if (lane < cdeg) {
                e = esrc[c0 + lane];
                float lg = asrc[e * HEADS + hd] + ad;
                lg = (lg > 0.f) ? lg : 0.2f * lg;
                pw = __expf(lg) * inv;
            }
            gather(e, pw, cdeg);
        }
    }

    // reduce across sub-groups
    #pragma unroll
    for (int m = LPE; m < 64; m <<= 1)
        #pragma unroll
        for (int i = 0; i < VEC; i++)
            acc[i] += __shfl_xor(acc[i], m);

    if constexpr (MODE == 0) {
        if (sub == 0) {
            const float* bp = bias + hd * C + cl * 4;
            float4 b = *(const float4*)bp;
            float r[4] = {acc[0] + b.x, acc[1] + b.y, acc[2] + b.z, acc[3] + b.w};
            #pragma unroll
            for (int j = 0; j < 4; j++)
                r[j] = (r[j] > 0.f) ? r[j] : (expf(r[j]) - 1.f);   // ELU
            ushort4 hv;
            hv.x = f2h(r[0]); hv.y = f2h(r[1]); hv.z = f2h(r[2]); hv.w = f2h(r[3]);
            *(ushort4*)(oh + (size_t)n * (HEADS * C) + hd * C + cl * 4) = hv;
        }
    } else {
        if (sub == 0) {
            float4 v0{acc[0], acc[1], acc[2], acc[3]};
            float4 v1{acc[4], acc[5], acc[6], acc[7]};
            *(float4*)&red[hd * 256 + cl * 8]     = v0;
            *(float4*)&red[hd * 256 + cl * 8 + 4] = v1;
        }
        __syncthreads();
        int tid = threadIdx.x;
        if (tid < 256) {
            float s = 0.f;
            #pragma unroll
            for (int hh = 0; hh < HEADS; hh++) s += red[hh * 256 + tid];
            outf[(size_t)n * 256 + tid] = s * 0.125f + bias[tid];
        }
    }
}

// ---------------- launch ----------------
extern "C" void kernel_launch(void* const* d_in, const int* in_sizes, int n_in,
                              void* d_out, int out_size, void* d_ws, size_t ws_size,
                              hipStream_t stream) {
    const float* x   = (const float*)d_in[0];
    const int*   ei  = (const int*)d_in[1];
    const float* W1  = (const float*)d_in[2];
    const float* as1 = (const float*)d_in[3];
    const float* ad1 = (const float*)d_in[4];
    const float* b1  = (const float*)d_in[5];
    const float* W2  = (const float*)d_in[6];
    const float* as2 = (const float*)d_in[7];
    const float* ad2 = (const float*)d_in[8];
    const float* b2  = (const float*)d_in[9];
    const float* W3  = (const float*)d_in[10];
    const float* as3 = (const float*)d_in[11];
    const float* ad3 = (const float*)d_in[12];
    const float* b3  = (const float*)d_in[13];
    float* out = (float*)d_out;

    int* deg    = (int*)d_ws;
    int* cursor = deg + 10240;
    int* rows   = cursor + 10240;
    int* esrc   = rows + 10240;
    float* asrc = (float*)(esrc + 170240);   // 81920 floats
    float* adst = asrc + 81920;              // 81920 floats (contiguous)
    u16* Hh     = (u16*)(adst + 81920);      // fp16 h, up to 10000*2048
    u16* Af     = Hh + (size_t)NNODES * 2048;   // fp16 GEMM input
    u16* Wf     = Af + (size_t)NNODES * 1024;   // fp16 weights

    hipMemsetAsync(deg, 0, 2 * 10240 * sizeof(int), stream);

    count_k<<<(TOT_E + 255) / 256, 256, 0, stream>>>(ei, deg);
    scan_k<<<1, 1024, 0, stream>>>(deg, rows);
    scatter_k<<<(TOT_E + 255) / 256, 256, 0, stream>>>(ei, rows, cursor, esrc);

    const int rowBlocks = (NNODES + 127) / 128;   // 79

    // ---- layer 1: IN=256 -> 8x64 concat ----
    cvt16_k<<<(NNODES * 256 / 4 + 255) / 256, 256, 0, stream>>>(x, Af, NNODES * 256 / 4);
    cvt16_k<<<(512 * 256 / 4 + 255) / 256, 256, 0, stream>>>(W1, Wf, 512 * 256 / 4);
    hipMemsetAsync(asrc, 0, 2 * 81920 * sizeof(float), stream);
    gemm_f16<<<dim3(4, rowBlocks), 256, 0, stream>>>(Af, Wf, Hh, NNODES, 512, 256,
                                                     as1, ad1, asrc, adst, 64);
    agg_k<64, 0><<<NNODES, 512, 0, stream>>>(Hh, asrc, adst, rows, esrc, b1, Af, nullptr);

    // ---- layer 2: 512 -> 8x128 concat ----
    cvt16_k<<<(1024 * 512 / 4 + 255) / 256, 256, 0, stream>>>(W2, Wf, 1024 * 512 / 4);
    hipMemsetAsync(asrc, 0, 2 * 81920 * sizeof(float), stream);
    gemm_f16<<<dim3(8, rowBlocks), 256, 0, stream>>>(Af, Wf, Hh, NNODES, 1024, 512,
                                                     as2, ad2, asrc, adst, 128);
    agg_k<128, 0><<<NNODES, 512, 0, stream>>>(Hh, asrc, adst, rows, esrc, b2, Af, nullptr);

    // ---- layer 3: 1024 -> 8x256 mean ----
    cvt16_k<<<(2048 * 1024 / 4 + 255) / 256, 256, 0, stream>>>(W3, Wf, 2048 * 1024 / 4);
    hipMemsetAsync(asrc, 0, 2 * 81920 * sizeof(float), stream);
    gemm_f16<<<dim3(16, rowBlocks), 256, 0, stream>>>(Af, Wf, Hh, NNODES, 2048, 1024,
                                                      as3, ad3, asrc, adst, 256);
    agg_k<256, 1><<<NNODES, 512, 0, stream>>>(Hh, asrc, adst, rows, esrc, b3, nullptr, out);
}

// Round 11
// 466.087 us; speedup vs baseline: 1.5283x; 1.0067x over previous
//
#include <hip/hip_runtime.h>
#include <cstdint>

#define NNODES 10000
#define NEDGES 160000
#define TOT_E  (NEDGES + NNODES)
#define HEADS  8

typedef unsigned short u16;
typedef __attribute__((ext_vector_type(8))) _Float16 h8;   // 8 fp16 (16B)
typedef __attribute__((ext_vector_type(4))) _Float16 h4;   // 4 fp16 (8B)
typedef __attribute__((ext_vector_type(4))) float f4;      // MFMA accumulator

// s_waitcnt imm: [3:0] vmcnt_lo, [6:4] expcnt, [11:8] lgkmcnt, [15:14] vmcnt_hi
#define WAIT_VM(n) __builtin_amdgcn_s_waitcnt(0x0F70 | (n))   // vmcnt(n), lgkm/exp no-wait

__device__ inline u16 f2h(float x) {
    union { _Float16 h; u16 u; } c; c.h = (_Float16)x; return c.u;
}

__device__ inline void gld16(const u16* g, u16* l) {
    __builtin_amdgcn_global_load_lds(
        (const __attribute__((address_space(1))) void*)g,
        (__attribute__((address_space(3))) void*)l, 16, 0, 0);
}

// ---------------- CSR build (dst-sorted) ----------------
__global__ void count_k(const int* __restrict__ ei, int* __restrict__ deg) {
    int i = blockIdx.x * 256 + threadIdx.x;
    if (i >= TOT_E) return;
    int dst = (i < NEDGES) ? ei[NEDGES + i] : (i - NEDGES);
    atomicAdd(deg + dst, 1);
}

__global__ __launch_bounds__(1024) void scan_k(const int* __restrict__ deg,
                                               int* __restrict__ rows) {
    __shared__ int buf[1024];
    int tid = threadIdx.x;
    int base = tid * 10;
    int loc[10]; int s = 0;
    #pragma unroll
    for (int j = 0; j < 10; j++) {
        int i = base + j;
        loc[j] = s;
        s += (i < NNODES) ? deg[i] : 0;
    }
    buf[tid] = s;
    __syncthreads();
    for (int off = 1; off < 1024; off <<= 1) {
        int t = (tid >= off) ? buf[tid - off] : 0;
        __syncthreads();
        buf[tid] += t;
        __syncthreads();
    }
    int ex = tid ? buf[tid - 1] : 0;
    #pragma unroll
    for (int j = 0; j < 10; j++) {
        int i = base + j;
        if (i < NNODES) rows[i] = ex + loc[j];
    }
    if (tid == 1023) rows[NNODES] = buf[1023];
}

__global__ void scatter_k(const int* __restrict__ ei, const int* __restrict__ rows,
                          int* __restrict__ cursor, int* __restrict__ esrc) {
    int i = blockIdx.x * 256 + threadIdx.x;
    if (i >= TOT_E) return;
    int src, dst;
    if (i < NEDGES) { src = ei[i]; dst = ei[NEDGES + i]; }
    else            { src = i - NEDGES; dst = src; }
    int pos = atomicAdd(cursor + dst, 1);
    esrc[rows[dst] + pos] = src;
}

// ---------------- fp32 -> fp16 convert ----------------
__global__ void cvt16_k(const float* __restrict__ in, u16* __restrict__ o, int n4) {
    int i = blockIdx.x * 256 + threadIdx.x;
    if (i >= n4) return;
    float4 v = ((const float4*)in)[i];
    ushort4 h;
    h.x = f2h(v.x); h.y = f2h(v.y); h.z = f2h(v.z); h.w = f2h(v.w);
    ((ushort4*)o)[i] = h;
}

// ---------------- fp16 MFMA GEMM, triple-buffered LDS, prefetch depth 2 ----
// C16[M,N] = fp16( A[M,K] * W[N,K]^T ). 128x128 tile, BK=32, 3 LDS buffers
// (3 x 16 KB). Steady state at iter k: stage tile k+2 -> s_waitcnt vmcnt(8)
// (tile k's loads, issued 2 iters (~400 cyc) ago, have landed; k+1/k+2 stay
// in flight) -> RAW s_barrier -> 16 MFMA from buf k%3 -> raw barrier.
// Prefetch distance 2 gives each staging load ~2 compute iters to cover the
// ~200-400 cyc L2 latency (r10's distance-1 WAIT_VM stalled every iter).
// 4-oct XOR swizzle: stage oct (lane&3)^((lane>>3)&3), read oct quad^((l15>>1)&3)
// -> conflict-free ds_read_b128. Epilogue: fp16 C + fused alpha partials.
__global__ __launch_bounds__(256) void gemm_f16(
    const u16* __restrict__ A, const u16* __restrict__ B,
    u16* __restrict__ C16, int M, int N, int K,
    const float* __restrict__ a_s, const float* __restrict__ a_d,
    float* __restrict__ asrc, float* __restrict__ adst, int Chead)
{
    __shared__ u16 sh[3][8192];               // [buf][A:0..4095 | B:4096..8191]
    const int t = threadIdx.x, lane = t & 63, w = t >> 6;
    const int row0 = blockIdx.y * 128, col0 = blockIdx.x * 128;
    const int wm = w & 1, wn = w >> 1;
    const int l15 = lane & 15, quad = lane >> 4;

    // staging: 16 chunks of 16 rows x 32 cols (1 KB); A: c=0..7, B: c=8..15.
    // wave w stages chunks 4w..4w+3; lane = row (lane>>2), swizzled oct.
    const int octg = (lane & 3) ^ ((lane >> 3) & 3);
    const int rl   = lane >> 2;               // 0..15
    const u16* gp[4]; int lofs[4];
    #pragma unroll
    for (int q = 0; q < 4; q++) {
        int c = w * 4 + q;
        if (c < 8) {
            int gr = row0 + c * 16 + rl; if (gr >= M) gr = M - 1;
            gp[q] = A + (size_t)gr * K + octg * 8;
            lofs[q] = c * 512;
        } else {
            int gc = col0 + (c - 8) * 16 + rl;    // N mult of 128 -> in bounds
            gp[q] = B + (size_t)gc * K + octg * 8;
            lofs[q] = 4096 + (c - 8) * 512;
        }
    }

    const int sw = (l15 >> 1) & 3;
    const int po = (quad ^ sw) * 8;           // swizzled physical oct (read)
    const int arow = (wm * 64 + l15) * 32;
    const int brow = 4096 + (wn * 64 + l15) * 32;

    f4 acc[4][4];
    #pragma unroll
    for (int i = 0; i < 4; i++)
        #pragma unroll
        for (int j = 0; j < 4; j++)
            acc[i][j] = (f4){0.f, 0.f, 0.f, 0.f};

    const int T = K >> 5;                     // >= 8 for all layers

    // prologue: stage tiles 0,1 into bufs 0,1
    #pragma unroll
    for (int q = 0; q < 4; q++) { gld16(gp[q], &sh[0][lofs[q]]); gp[q] += 32; }
    #pragma unroll
    for (int q = 0; q < 4; q++) { gld16(gp[q], &sh[1][lofs[q]]); gp[q] += 32; }

    for (int k = 0; k < T; k++) {
        if (k + 2 < T) {
            u16* dst = &sh[(k + 2) % 3][0];
            #pragma unroll
            for (int q = 0; q < 4; q++) { gld16(gp[q], dst + lofs[q]); gp[q] += 32; }
            WAIT_VM(8);                       // tile k landed; k+1,k+2 in flight
        } else if (k + 2 == T) {
            WAIT_VM(4);                       // tile k landed; k+1 in flight
        } else {
            WAIT_VM(0);
        }
        __builtin_amdgcn_s_barrier();         // raw: no compiler vmcnt(0) drain

        const u16* sa = &sh[k % 3][0];
        h8 a[4];
        #pragma unroll
        for (int i = 0; i < 4; i++)
            a[i] = *(const h8*)&sa[arow + i * 512 + po];
        #pragma unroll
        for (int j = 0; j < 4; j++) {
            h8 b = *(const h8*)&sa[brow + j * 512 + po];
            #pragma unroll
            for (int i = 0; i < 4; i++)
                acc[i][j] = __builtin_amdgcn_mfma_f32_16x16x32_f16(a[i], b, acc[i][j], 0, 0, 0);
        }
        __builtin_amdgcn_s_barrier();         // reads done before buf reuse (k+3 writes k%3)
    }

    // alpha coefficients for this wave's 64-channel span (within one head)
    const int span0 = col0 + wn * 64;
    const int hd = span0 / Chead;
    float av[4], dv[4];
    #pragma unroll
    for (int j = 0; j < 4; j++) {
        av[j] = a_s[span0 + j * 16 + l15];
        dv[j] = a_d[span0 + j * 16 + l15];
    }

    // epilogue: C/D layout col=lane&15, row=quad*4+reg
    #pragma unroll
    for (int i = 0; i < 4; i++) {
        #pragma unroll
        for (int r = 0; r < 4; r++) {
            int gr = row0 + wm * 64 + i * 16 + quad * 4 + r;
            float s1 = 0.f, s2 = 0.f;
            #pragma unroll
            for (int j = 0; j < 4; j++) {
                float v = acc[i][j][r];
                s1 += v * av[j];
                s2 += v * dv[j];
            }
            #pragma unroll
            for (int m = 1; m < 16; m <<= 1) {
                s1 += __shfl_xor(s1, m);
                s2 += __shfl_xor(s2, m);
            }
            if (gr < M) {
                u16* cp = C16 + (size_t)gr * N + span0 + l15;
                #pragma unroll
                for (int j = 0; j < 4; j++)
                    cp[j * 16] = f2h(acc[i][j][r]);
                if (l15 == 0) {
                    atomicAdd(asrc + gr * HEADS + hd, s1);
                    atomicAdd(adst + gr * HEADS + hd, s2);
                }
            }
        }
    }
}

// ---------------- softmax + aggregation (r9 form — VEC=4, low VGPR) --------
// One block per node, 8 waves = 8 heads; h gathered as fp16 (all layers).
// No max-subtraction (logits bounded; p/s scale-invariant). LPE = C/4 lanes
// per edge (8B h4 loads), U batched edge-passes in flight.
// MODE 0: concat +bias +ELU -> fp16 plane. MODE 1: LDS head-mean + bias.
template<int C, int MODE>
__global__ __launch_bounds__(512) void agg_k(const u16* __restrict__ h16,
                                             const float* __restrict__ asrc,
                                             const float* __restrict__ adst,
                                             const int* __restrict__ rows,
                                             const int* __restrict__ esrc,
                                             const float* __restrict__ bias,
                                             u16* __restrict__ oh,
                                             float* __restrict__ outf) {
    constexpr int LPE = C / 4;
    constexpr int EPW = 64 / LPE;
    constexpr int U   = (LPE == 64) ? 16 : (LPE == 32) ? 12 : 8;
    __shared__ float red[MODE == 1 ? HEADS * 256 : 8];

    const int n    = blockIdx.x;
    const int hd   = threadIdx.x >> 6;
    const int lane = threadIdx.x & 63;
    const int sub  = lane / LPE;
    const int cl   = lane % LPE;
    const int beg = rows[n], end = rows[n + 1], deg = end - beg;
    const float ad = adst[n * HEADS + hd];

    float4 acc = {0.f, 0.f, 0.f, 0.f};

    auto gather = [&](int e, float pw, int cdeg) {
        for (int j = 0; j < cdeg; j += EPW * U) {
            int   sn[U]; float wg[U];
            #pragma unroll
            for (int u = 0; u < U; u++) {
                int idx = j + sub + EPW * u;
                int   ss = __shfl(e, idx);
                float ww = __shfl(pw, idx);
                bool ok = idx < cdeg;
                sn[u] = ok ? ss : 0;
                wg[u] = ok ? ww : 0.f;
            }
            h4 v[U];
            #pragma unroll
            for (int u = 0; u < U; u++)
                v[u] = *(const h4*)(h16 + (size_t)sn[u] * (HEADS * C) + hd * C + cl * 4);
            #pragma unroll
            for (int u = 0; u < U; u++) {
                acc.x += wg[u] * (float)v[u].x; acc.y += wg[u] * (float)v[u].y;
                acc.z += wg[u] * (float)v[u].z; acc.w += wg[u] * (float)v[u].w;
            }
        }
    };

    if (deg <= 64) {
        int e = 0; float p = 0.f;
        if (lane < deg) {
            e = esrc[beg + lane];
            float lg = asrc[e * HEADS + hd] + ad;
            lg = (lg > 0.f) ? lg : 0.2f * lg;
            p = __expf(lg);
        }
        float s = p;
        #pragma unroll
        for (int off = 32; off; off >>= 1) s += __shfl_xor(s, off);
        float pw = p / (s + 1e-16f);
        gather(e, pw, deg);
    } else {
        float ssum = 0.f;
        for (int i = beg + lane; i < end; i += 64) {
            float lg = asrc[esrc[i] * HEADS + hd] + ad;
            lg = (lg > 0.f) ? lg : 0.2f * lg;
            ssum += __expf(lg);
        }
        #pragma unroll
        for (int off = 32; off; off >>= 1) ssum += __shfl_xor(ssum, off);
        float inv = 1.f / (ssum + 1e-16f);
        for (int c0 = beg; c0 < end; c0 += 64) {
            int cdeg = min(64, end - c0);
            int e = 0; float pw = 0.f;
            if (lane < cdeg) {
                e = esrc[c0 + lane];
                float lg = asrc[e * HEADS + hd] + ad;
                lg = (lg > 0.f) ? lg : 0.2f * lg;
                pw = __expf(lg) * inv;
            }
            gather(e, pw, cdeg);
        }
    }

    #pragma unroll
    for (int m = LPE; m < 64; m <<= 1) {
        acc.x += __shfl_xor(acc.x, m); acc.y += __shfl_xor(acc.y, m);
        acc.z += __shfl_xor(acc.z, m); acc.w += __shfl_xor(acc.w, m);
    }

    if constexpr (MODE == 0) {
        if (sub == 0) {
            const float* bp = bias + hd * C + cl * 4;
            float4 b = *(const float4*)bp;
            float r[4] = {acc.x + b.x, acc.y + b.y, acc.z + b.z, acc.w + b.w};
            #pragma unroll
            for (int j = 0; j < 4; j++)
                r[j] = (r[j] > 0.f) ? r[j] : (expf(r[j]) - 1.f);   // ELU
            ushort4 hv;
            hv.x = f2h(r[0]); hv.y = f2h(r[1]); hv.z = f2h(r[2]); hv.w = f2h(r[3]);
            *(ushort4*)(oh + (size_t)n * (HEADS * C) + hd * C + cl * 4) = hv;
        }
    } else {
        *(float4*)&red[hd * 256 + lane * 4] = acc;
        __syncthreads();
        int tid = threadIdx.x;
        if (tid < 256) {
            float s = 0.f;
            #pragma unroll
            for (int hh = 0; hh < HEADS; hh++) s += red[hh * 256 + tid];
            outf[(size_t)n * 256 + tid] = s * 0.125f + bias[tid];
        }
    }
}

// ---------------- launch ----------------
extern "C" void kernel_launch(void* const* d_in, const int* in_sizes, int n_in,
                              void* d_out, int out_size, void* d_ws, size_t ws_size,
                              hipStream_t stream) {
    const float* x   = (const float*)d_in[0];
    const int*   ei  = (const int*)d_in[1];
    const float* W1  = (const float*)d_in[2];
    const float* as1 = (const float*)d_in[3];
    const float* ad1 = (const float*)d_in[4];
    const float* b1  = (const float*)d_in[5];
    const float* W2  = (const float*)d_in[6];
    const float* as2 = (const float*)d_in[7];
    const float* ad2 = (const float*)d_in[8];
    const float* b2  = (const float*)d_in[9];
    const float* W3  = (const float*)d_in[10];
    const float* as3 = (const float*)d_in[11];
    const float* ad3 = (const float*)d_in[12];
    const float* b3  = (const float*)d_in[13];
    float* out = (float*)d_out;

    int* deg    = (int*)d_ws;
    int* cursor = deg + 10240;
    int* rows   = cursor + 10240;
    int* esrc   = rows + 10240;
    float* asrc = (float*)(esrc + 170240);   // 81920 floats
    float* adst = asrc + 81920;              // 81920 floats (contiguous)
    u16* Hh     = (u16*)(adst + 81920);      // fp16 h, up to 10000*2048
    u16* Af     = Hh + (size_t)NNODES * 2048;   // fp16 GEMM input
    u16* Wf     = Af + (size_t)NNODES * 1024;   // fp16 weights

    hipMemsetAsync(deg, 0, 2 * 10240 * sizeof(int), stream);

    count_k<<<(TOT_E + 255) / 256, 256, 0, stream>>>(ei, deg);
    scan_k<<<1, 1024, 0, stream>>>(deg, rows);
    scatter_k<<<(TOT_E + 255) / 256, 256, 0, stream>>>(ei, rows, cursor, esrc);

    const int rowBlocks = (NNODES + 127) / 128;   // 79

    // ---- layer 1: IN=256 -> 8x64 concat ----
    cvt16_k<<<(NNODES * 256 / 4 + 255) / 256, 256, 0, stream>>>(x, Af, NNODES * 256 / 4);
    cvt16_k<<<(512 * 256 / 4 + 255) / 256, 256, 0, stream>>>(W1, Wf, 512 * 256 / 4);
    hipMemsetAsync(asrc, 0, 2 * 81920 * sizeof(float), stream);
    gemm_f16<<<dim3(4, rowBlocks), 256, 0, stream>>>(Af, Wf, Hh, NNODES, 512, 256,
                                                     as1, ad1, asrc, adst, 64);
    agg_k<64, 0><<<NNODES, 512, 0, stream>>>(Hh, asrc, adst, rows, esrc, b1, Af, nullptr);

    // ---- layer 2: 512 -> 8x128 concat ----
    cvt16_k<<<(1024 * 512 / 4 + 255) / 256, 256, 0, stream>>>(W2, Wf, 1024 * 512 / 4);
    hipMemsetAsync(asrc, 0, 2 * 81920 * sizeof(float), stream);
    gemm_f16<<<dim3(8, rowBlocks), 256, 0, stream>>>(Af, Wf, Hh, NNODES, 1024, 512,
                                                     as2, ad2, asrc, adst, 128);
    agg_k<128, 0><<<NNODES, 512, 0, stream>>>(Hh, asrc, adst, rows, esrc, b2, Af, nullptr);

    // ---- layer 3: 1024 -> 8x256 mean ----
    cvt16_k<<<(2048 * 1024 / 4 + 255) / 256, 256, 0, stream>>>(W3, Wf, 2048 * 1024 / 4);
    hipMemsetAsync(asrc, 0, 2 * 81920 * sizeof(float), stream);
    gemm_f16<<<dim3(16, rowBlocks), 256, 0, stream>>>(Af, Wf, Hh, NNODES, 2048, 1024,
                                                      as3, ad3, asrc, adst, 256);
    agg_k<256, 1><<<NNODES, 512, 0, stream>>>(Hh, asrc, adst, rows, esrc, b3, nullptr, out);
}